// Round 4
// baseline (834.788 us; speedup 1.0000x reference)
//
#include <hip/hip_runtime.h>

// GCN 3-layer forward on MI355X.
// Pipeline (A_hat (X W) = (A_hat X) W):
//   aggx:  Y1 = A_hat X          GEMM1: H1s = dinv*relu(Y1 W1 + b1)
//   agg256c: Y2 = A_hat H1       MLP23: G3 = dinv*((relu(Y2 W2 + b2)) W3)  [fused]
//   aggouts64: out = dinv[c]*(sum G3[r]+G3[c]) + b3 (f32)
// Gather wall (measured r0-r3): L2-outbound random-fetch path ~3.3-3.8 TB/s;
// FETCH is the lever. r3: 128B chunks -> per-XCD slab 12.8MB >> 4MiB L2 ->
// ~3.2x compulsory refetch. This round: 64B chunks (HID=256 = 8 x 32bf16),
// cell = bid&7 -> XCD; slab 6.4MB if fetch granule is 64B (free bet: provably
// neutral if granule is 128B - same line footprint).
// MLP23 fusion: H2 tile (128x256 bf16, 64KB) stays in LDS (XOR-swizzle
// (row&7)<<4 on write+read, m214 pattern); W3 (64KB, L2-resident) read direct.
// CSR build: atomics only on memset-initialized arrays; rowidx needs no
// memset (every slot [0,E) written exactly once); rowidx clamped at read.

#define IN_F 50
#define HID  256
#define OUT_F 121
#define KP1  64      // layer-1 width padded 50->64
#define NP3  128     // layer-3 N padded 121->128
#define MPAD 100096  // 782 * 128

typedef __attribute__((ext_vector_type(8))) short bf16x8;
typedef __attribute__((ext_vector_type(4))) float f32x4;

__device__ __forceinline__ float bf2f(unsigned short u) {
    union { unsigned int i; float f; } x; x.i = ((unsigned int)u) << 16; return x.f;
}
__device__ __forceinline__ unsigned short f2bf(float f) {
    union { float f; unsigned int i; } x; x.f = f;
    unsigned int r = x.i + 0x7FFFu + ((x.i >> 16) & 1u);  // RNE
    return (unsigned short)(r >> 16);
}

__device__ __forceinline__ void gl2lds16(const void* g, void* l) {
    __builtin_amdgcn_global_load_lds(
        (const __attribute__((address_space(1))) void*)g,
        (__attribute__((address_space(3))) void*)l, 16, 0, 0);
}

// ---- edge dtype detection (int64 vs int32), 64-lane parallel ----------------
__global__ void k_detect(const int* __restrict__ ei, int* __restrict__ flag, int N) {
    int i = threadIdx.x;
    int lo = ei[2 * i], hi = ei[2 * i + 1];
    int bad = (hi != 0) || ((unsigned)lo >= (unsigned)N);
    unsigned long long m = __ballot(bad);
    if (threadIdx.x == 0) *flag = (m == 0ULL) ? 1 : 0;
}

// ---- CSR build --------------------------------------------------------------

__global__ void k_count(const int* __restrict__ ei, const int* __restrict__ flag,
                        int* __restrict__ cnt, int E, int N) {
    int t = blockIdx.x * blockDim.x + threadIdx.x;
    if (t >= E) return;
    int f = *flag;
    int c = f ? ei[2 * (E + t)] : ei[E + t];
    c = min(max(c, 0), N - 1);
    atomicAdd(&cnt[c], 1);
}

__global__ __launch_bounds__(1024) void k_scan(const int* __restrict__ cnt,
                                               int* __restrict__ offs,
                                               float* __restrict__ dinv, int n) {
    __shared__ int wsum[16];
    __shared__ int s_carry;
    int lane = threadIdx.x & 63, wid = threadIdx.x >> 6;
    if (threadIdx.x == 0) s_carry = 0;
    __syncthreads();
    for (int base = 0; base < n; base += 4096) {
        int i0 = base + (int)threadIdx.x * 4;
        int v0 = (i0 + 0 < n) ? cnt[i0 + 0] : 0;
        int v1 = (i0 + 1 < n) ? cnt[i0 + 1] : 0;
        int v2 = (i0 + 2 < n) ? cnt[i0 + 2] : 0;
        int v3 = (i0 + 3 < n) ? cnt[i0 + 3] : 0;
        int s1 = v0 + v1, s2 = s1 + v2, tsum = s2 + v3;
        int x = tsum;
        #pragma unroll
        for (int d = 1; d < 64; d <<= 1) {
            int y = __shfl_up(x, d, 64);
            if (lane >= d) x += y;
        }
        if (lane == 63) wsum[wid] = x;
        __syncthreads();
        int wpre = 0;
        #pragma unroll
        for (int j = 0; j < 16; j++) wpre += (j < wid) ? wsum[j] : 0;
        int carry = s_carry;
        int e0 = carry + wpre + x - tsum;
        if (i0 + 0 < n) { offs[i0+0]=e0;    dinv[i0+0]=rsqrtf((float)(v0+1)); }
        if (i0 + 1 < n) { offs[i0+1]=e0+v0; dinv[i0+1]=rsqrtf((float)(v1+1)); }
        if (i0 + 2 < n) { offs[i0+2]=e0+s1; dinv[i0+2]=rsqrtf((float)(v2+1)); }
        if (i0 + 3 < n) { offs[i0+3]=e0+s2; dinv[i0+3]=rsqrtf((float)(v3+1)); }
        __syncthreads();
        if (threadIdx.x == 1023) s_carry = carry + wpre + x;
        __syncthreads();
    }
    if (threadIdx.x == 0) offs[n] = s_carry;
}

__global__ void k_fill(const int* __restrict__ ei, const int* __restrict__ flag,
                       const int* __restrict__ offs,
                       int* __restrict__ fillc, int* __restrict__ rowidx, int E, int N) {
    int t = blockIdx.x * blockDim.x + threadIdx.x;
    if (t >= E) return;
    int f = *flag;
    int c = f ? ei[2 * (E + t)] : ei[E + t];
    int r = f ? ei[2 * t] : ei[t];
    c = min(max(c, 0), N - 1);
    r = min(max(r, 0), N - 1);
    int pos = offs[c] + atomicAdd(&fillc[c], 1);
    if ((unsigned)pos < (unsigned)E) rowidx[pos] = r;
}

// ---- input prep (padx + 3 weight transposes, one launch) --------------------
__global__ void k_prep(const float* __restrict__ x, const float* __restrict__ dinv,
                       unsigned short* __restrict__ Xs,
                       const float* __restrict__ W1, unsigned short* __restrict__ Bt1,
                       const float* __restrict__ W2, unsigned short* __restrict__ Bt2,
                       const float* __restrict__ W3, unsigned short* __restrict__ Bt3,
                       int N) {
    int bid = blockIdx.x;
    int npadx = (N * KP1 + 255) / 256;
    if (bid < npadx) {
        int idx = bid * 256 + (int)threadIdx.x;
        if (idx < N * KP1) {
            int node = idx >> 6, k = idx & 63;
            Xs[idx] = (k < IN_F) ? f2bf(dinv[node] * x[node * IN_F + k]) : (unsigned short)0;
        }
        return;
    }
    bid -= npadx;
    if (bid < (HID * KP1) / 256) {          // Bt1 [256][64]
        int idx = bid * 256 + (int)threadIdx.x;
        int nn = idx >> 6, k = idx & 63;
        Bt1[idx] = (k < IN_F) ? f2bf(W1[k * HID + nn]) : (unsigned short)0;
        return;
    }
    bid -= (HID * KP1) / 256;
    if (bid < (HID * HID) / 256) {          // Bt2 [256][256]
        int idx = bid * 256 + (int)threadIdx.x;
        int nn = idx >> 8, k = idx & 255;
        Bt2[idx] = f2bf(W2[k * HID + nn]);
        return;
    }
    bid -= (HID * HID) / 256;
    {                                        // Bt3 [128][256]
        int idx = bid * 256 + (int)threadIdx.x;
        int nn = idx >> 8, k = idx & 255;
        Bt3[idx] = (nn < OUT_F) ? f2bf(W3[k * OUT_F + nn]) : (unsigned short)0;
    }
}

// ---- LDS-tiled GEMM (m97 structure) — layer 1 only --------------------------
__global__ __launch_bounds__(256) void k_gemm_lds(const unsigned short* __restrict__ A,
                                                  const unsigned short* __restrict__ Bt,
                                                  const float* __restrict__ dinv,
                                                  const float* __restrict__ bias,
                                                  unsigned short* __restrict__ C,
                                                  int K, int Nout,
                                                  int BIAS, int RELU, int SCALE) {
    __shared__ char lds[16384];   // A tile [128][32] bf16 @0, B tile @8192
    const int tid = threadIdx.x;
    const int wid = tid >> 6, lane = tid & 63;
    const int wm = wid & 1, wn = wid >> 1;
    const int quad = lane >> 4, ml = lane & 15;
    const int m0 = blockIdx.x * 128;
    const int n0g = blockIdx.y * 128;

    f32x4 acc[4][4];
    #pragma unroll
    for (int a = 0; a < 4; a++)
        #pragma unroll
        for (int b = 0; b < 4; b++) acc[a][b] = (f32x4){0.f, 0.f, 0.f, 0.f};

    for (int kk = 0; kk < K; kk += 32) {
        #pragma unroll
        for (int r = 0; r < 2; r++) {
            int c = r * 256 + tid;
            int row = c >> 2, q = c & 3;
            gl2lds16(A  + (size_t)(m0  + row) * K + kk + q * 8, lds + c * 16);
            gl2lds16(Bt + (size_t)(n0g + row) * K + kk + q * 8, lds + 8192 + c * 16);
        }
        __syncthreads();
        bf16x8 af[4], bfv[4];
        #pragma unroll
        for (int mf = 0; mf < 4; mf++)
            af[mf] = *(const bf16x8*)(lds + ((wm * 64 + mf * 16 + ml) * 64 + quad * 16));
        #pragma unroll
        for (int nf = 0; nf < 4; nf++)
            bfv[nf] = *(const bf16x8*)(lds + 8192 + ((wn * 64 + nf * 16 + ml) * 64 + quad * 16));
        #pragma unroll
        for (int mf = 0; mf < 4; mf++)
            #pragma unroll
            for (int nf = 0; nf < 4; nf++)
                acc[mf][nf] = __builtin_amdgcn_mfma_f32_16x16x32_bf16(af[mf], bfv[nf], acc[mf][nf], 0, 0, 0);
        __syncthreads();
    }

    #pragma unroll
    for (int mf = 0; mf < 4; mf++) {
        int r0 = m0 + wm * 64 + mf * 16 + quad * 4;
        float dd[4] = {1.f, 1.f, 1.f, 1.f};
        if (SCALE) { dd[0]=dinv[r0]; dd[1]=dinv[r0+1]; dd[2]=dinv[r0+2]; dd[3]=dinv[r0+3]; }
        #pragma unroll
        for (int nf = 0; nf < 4; nf++) {
            int col = n0g + wn * 64 + nf * 16 + ml;
            float bb = BIAS ? bias[col] : 0.f;
            #pragma unroll
            for (int i = 0; i < 4; i++) {
                float v = acc[mf][nf][i] + bb;
                if (RELU) v = fmaxf(v, 0.f);
                v *= dd[i];
                C[(size_t)(r0 + i) * Nout + col] = f2bf(v);
            }
        }
    }
}

// ---- FUSED GEMM2+GEMM3: G3 = dinv * (relu(Y2 W2 + b2) W3) -------------------
// Block: 128 rows, 4 waves (2x2). Phase 1: H2 tile (128x256) accumulated in
// regs via LDS-staged A/B2 slices; relu(+b2) -> H2 in LDS bf16, XOR-swizzled
// byte ^= (row&7)<<4 (conflict fix for phase-2 row-major A-frag reads).
// Phase 2: K-loop reads A-frags from H2-LDS, B-frags direct from global Bt3
// (64KB, L2-resident), no barriers needed.
__global__ __launch_bounds__(256) void k_mlp23(const unsigned short* __restrict__ A,
                                               const unsigned short* __restrict__ B2t,
                                               const unsigned short* __restrict__ B3t,
                                               const float* __restrict__ b2,
                                               const float* __restrict__ dinv,
                                               unsigned short* __restrict__ G) {
    __shared__ char lds[65536];  // phase1 staging: A[128][32]@0, B2[256][32]@8192 (24KB)
                                 // then H2 [128][256] bf16 @0 (64KB, swizzled)
    const int tid = threadIdx.x;
    const int wid = tid >> 6, lane = tid & 63;
    const int wm = wid & 1, wn = wid >> 1;
    const int quad = lane >> 4, ml = lane & 15;
    const int m0 = blockIdx.x * 128;

    f32x4 acc1[4][8];
    #pragma unroll
    for (int a = 0; a < 4; a++)
        #pragma unroll
        for (int b = 0; b < 8; b++) acc1[a][b] = (f32x4){0.f, 0.f, 0.f, 0.f};

    for (int kk = 0; kk < HID; kk += 32) {
        #pragma unroll
        for (int r = 0; r < 2; r++) {
            int c = r * 256 + tid;
            int row = c >> 2, q = c & 3;
            gl2lds16(A + (size_t)(m0 + row) * HID + kk + q * 8, lds + c * 16);
        }
        #pragma unroll
        for (int r = 0; r < 4; r++) {
            int c = r * 256 + tid;
            int nn = c >> 2, q = c & 3;
            gl2lds16(B2t + (size_t)nn * HID + kk + q * 8, lds + 8192 + c * 16);
        }
        __syncthreads();
        bf16x8 af[4], bv[8];
        #pragma unroll
        for (int mf = 0; mf < 4; mf++)
            af[mf] = *(const bf16x8*)(lds + ((wm * 64 + mf * 16 + ml) * 64 + quad * 16));
        #pragma unroll
        for (int nf = 0; nf < 8; nf++)
            bv[nf] = *(const bf16x8*)(lds + 8192 + ((wn * 128 + nf * 16 + ml) * 64 + quad * 16));
        #pragma unroll
        for (int mf = 0; mf < 4; mf++)
            #pragma unroll
            for (int nf = 0; nf < 8; nf++)
                acc1[mf][nf] = __builtin_amdgcn_mfma_f32_16x16x32_bf16(af[mf], bv[nf], acc1[mf][nf], 0, 0, 0);
        __syncthreads();
    }

    // H2 = relu(acc1 + b2) -> LDS bf16, swizzled
    #pragma unroll
    for (int nf = 0; nf < 8; nf++) {
        int col = wn * 128 + nf * 16 + ml;
        float bb = b2[col];
        #pragma unroll
        for (int mf = 0; mf < 4; mf++) {
            int rl = wm * 64 + mf * 16 + quad * 4;
            #pragma unroll
            for (int i = 0; i < 4; i++) {
                int row = rl + i;
                int byte = (row * 512 + col * 2) ^ ((row & 7) << 4);
                *(unsigned short*)(lds + byte) = f2bf(fmaxf(acc1[mf][nf][i] + bb, 0.f));
            }
        }
    }
    __syncthreads();

    // phase 2: G3 tile (128x128), A from H2-LDS, B direct from global Bt3
    f32x4 acc2[4][4];
    #pragma unroll
    for (int a = 0; a < 4; a++)
        #pragma unroll
        for (int b = 0; b < 4; b++) acc2[a][b] = (f32x4){0.f, 0.f, 0.f, 0.f};

    for (int kk = 0; kk < HID; kk += 32) {
        bf16x8 af2[4], bv2[4];
        #pragma unroll
        for (int mf = 0; mf < 4; mf++) {
            int row = wm * 64 + mf * 16 + ml;
            int byte = (row * 512 + kk * 2 + quad * 16) ^ ((row & 7) << 4);
            af2[mf] = *(const bf16x8*)(lds + byte);
        }
        #pragma unroll
        for (int nf = 0; nf < 4; nf++)
            bv2[nf] = *(const bf16x8*)(B3t + (size_t)(wn * 64 + nf * 16 + ml) * HID + kk + quad * 8);
        #pragma unroll
        for (int mf = 0; mf < 4; mf++)
            #pragma unroll
            for (int nf = 0; nf < 4; nf++)
                acc2[mf][nf] = __builtin_amdgcn_mfma_f32_16x16x32_bf16(af2[mf], bv2[nf], acc2[mf][nf], 0, 0, 0);
    }

    #pragma unroll
    for (int mf = 0; mf < 4; mf++) {
        int r0 = m0 + wm * 64 + mf * 16 + quad * 4;
        float dd[4] = {dinv[r0], dinv[r0+1], dinv[r0+2], dinv[r0+3]};
        #pragma unroll
        for (int nf = 0; nf < 4; nf++) {
            int col = wn * 64 + nf * 16 + ml;
            #pragma unroll
            for (int i = 0; i < 4; i++)
                G[(size_t)(r0 + i) * NP3 + col] = f2bf(acc2[mf][nf][i] * dd[i]);
        }
    }
}

// ---- aggregation kernels ----------------------------------------------------
__device__ __forceinline__ int rclamp(int r, int N) { return min(max(r, 0), N - 1); }

// aggx: rows 64 bf16 = 128B -> 8 lanes/row, 8 nodes/wave, 32 nodes/block.
__global__ void k_aggx(const unsigned short* __restrict__ Xs,
                       const int* __restrict__ offs, const int* __restrict__ rowidx,
                       const float* __restrict__ dinv, unsigned short* __restrict__ Y, int N) {
    int wid = threadIdx.x >> 6, lane = threadIdx.x & 63;
    int sub = lane >> 3, sl = lane & 7;
    int node = blockIdx.x * 32 + wid * 8 + sub;
    int nc = min(node, N - 1);
    int c = sl * 8;
    bf16x8 s = *(const bf16x8*)(Xs + (size_t)nc * KP1 + c);
    float a[8];
    #pragma unroll
    for (int k = 0; k < 8; k++) a[k] = bf2f((unsigned short)s[k]);
    int e = offs[nc], end = offs[nc + 1];
    if (node >= N) { e = 0; end = 0; }
    while (__any(e < end)) {
        int r[4]; float m[4];
        #pragma unroll
        for (int j = 0; j < 4; j++) {
            int idx = e + j;
            m[j] = (idx < end) ? 1.f : 0.f;
            idx = min(idx, end - 1); idx = max(idx, 0);
            r[j] = rclamp(rowidx[idx], N);
        }
        bf16x8 u[4];
        #pragma unroll
        for (int j = 0; j < 4; j++)
            u[j] = *(const bf16x8*)(Xs + (size_t)r[j] * KP1 + c);
        #pragma unroll
        for (int j = 0; j < 4; j++)
            #pragma unroll
            for (int k = 0; k < 8; k++)
                a[k] = fmaf(bf2f((unsigned short)u[j][k]), m[j], a[k]);
        e += 4;
    }
    if (node < N) {
        float dv = dinv[node];
        bf16x8 o;
        #pragma unroll
        for (int k = 0; k < 8; k++) o[k] = (short)f2bf(a[k] * dv);
        *(bf16x8*)(Y + (size_t)node * KP1 + c) = o;
    }
}

// agg256c: 64B-chunk gather for 256-wide rows. 8 chunks of 32 bf16 (64B);
// cell = bid&7 = chunk -> XCD. 4 lanes/row (16B each), 16 nodes/wave, 64/block.
__global__ void k_agg256c(const unsigned short* __restrict__ Hn,
                          const int* __restrict__ offs, const int* __restrict__ rowidx,
                          const float* __restrict__ dinv, unsigned short* __restrict__ Y,
                          int N) {
    int chunk = blockIdx.x & 7;
    int idx = blockIdx.x >> 3;
    int wid = threadIdx.x >> 6, lane = threadIdx.x & 63;
    int sub = lane >> 2, sl = lane & 3;
    int node = idx * 64 + wid * 16 + sub;
    int ok = node < N;
    int nc = ok ? node : N - 1;
    int c = chunk * 32 + sl * 8;
    bf16x8 s = *(const bf16x8*)(Hn + (size_t)nc * HID + c);
    float a[8];
    #pragma unroll
    for (int k = 0; k < 8; k++) a[k] = bf2f((unsigned short)s[k]);
    int e = offs[nc], end = offs[nc + 1];
    if (!ok) { e = 0; end = 0; }
    while (__any(e < end)) {
        int r[4]; float m[4];
        #pragma unroll
        for (int j = 0; j < 4; j++) {
            int idx2 = e + j;
            m[j] = (idx2 < end) ? 1.f : 0.f;
            idx2 = min(idx2, end - 1); idx2 = max(idx2, 0);
            r[j] = rclamp(rowidx[idx2], N);
        }
        bf16x8 u[4];
        #pragma unroll
        for (int j = 0; j < 4; j++)
            u[j] = *(const bf16x8*)(Hn + (size_t)r[j] * HID + c);
        #pragma unroll
        for (int j = 0; j < 4; j++)
            #pragma unroll
            for (int k = 0; k < 8; k++)
                a[k] = fmaf(bf2f((unsigned short)u[j][k]), m[j], a[k]);
        e += 4;
    }
    if (ok) {
        float dv = dinv[node];
        bf16x8 o;
        #pragma unroll
        for (int k = 0; k < 8; k++) o[k] = (short)f2bf(a[k] * dv);
        *(bf16x8*)(Y + (size_t)node * HID + c) = o;
    }
}

// aggouts64: 64B-chunk gather for 128-wide rows. 4 chunks x 2 dest-halves;
// cell = bid&7: chunk = cell>>1, half = cell&1. 16 nodes/wave.
__global__ void k_aggouts64(const unsigned short* __restrict__ G,
                            const int* __restrict__ offs, const int* __restrict__ rowidx,
                            const float* __restrict__ dinv, const float* __restrict__ bias,
                            float* __restrict__ out, int N, int half_n) {
    int cell = blockIdx.x & 7;
    int chunk = cell >> 1, half = cell & 1;
    int idx = blockIdx.x >> 3;
    int wid = threadIdx.x >> 6, lane = threadIdx.x & 63;
    int sub = lane >> 2, sl = lane & 3;
    int node = half * half_n + idx * 64 + wid * 16 + sub;
    int hi_end = min((half + 1) * half_n, N);
    int ok = node < hi_end;
    int nc = ok ? node : hi_end - 1;
    int c = chunk * 32 + sl * 8;
    bf16x8 s = *(const bf16x8*)(G + (size_t)nc * NP3 + c);
    float a[8];
    #pragma unroll
    for (int k = 0; k < 8; k++) a[k] = bf2f((unsigned short)s[k]);
    int e = offs[nc], end = offs[nc + 1];
    if (!ok) { e = 0; end = 0; }
    while (__any(e < end)) {
        int r[4]; float m[4];
        #pragma unroll
        for (int j = 0; j < 4; j++) {
            int idx2 = e + j;
            m[j] = (idx2 < end) ? 1.f : 0.f;
            idx2 = min(idx2, end - 1); idx2 = max(idx2, 0);
            r[j] = rclamp(rowidx[idx2], N);
        }
        bf16x8 u[4];
        #pragma unroll
        for (int j = 0; j < 4; j++)
            u[j] = *(const bf16x8*)(G + (size_t)r[j] * NP3 + c);
        #pragma unroll
        for (int j = 0; j < 4; j++)
            #pragma unroll
            for (int k = 0; k < 8; k++)
                a[k] = fmaf(bf2f((unsigned short)u[j][k]), m[j], a[k]);
        e += 4;
    }
    if (ok) {
        float dv = dinv[node];
        #pragma unroll
        for (int k = 0; k < 8; k++) {
            int col = c + k;
            if (col < OUT_F)
                out[(size_t)node * OUT_F + col] = fmaf(a[k], dv, bias[col]);
        }
    }
}

// ---- launch -----------------------------------------------------------------

extern "C" void kernel_launch(void* const* d_in, const int* in_sizes, int n_in,
                              void* d_out, int out_size, void* d_ws, size_t ws_size,
                              hipStream_t stream) {
    const float* x  = (const float*)d_in[0];
    const int*   ei = (const int*)d_in[1];
    const float* W1 = (const float*)d_in[2];
    const float* b1 = (const float*)d_in[3];
    const float* W2 = (const float*)d_in[4];
    const float* b2 = (const float*)d_in[5];
    const float* W3 = (const float*)d_in[6];
    const float* b3 = (const float*)d_in[7];
    float* out = (float*)d_out;

    const int N = in_sizes[0] / IN_F;     // 100000
    const int E = in_sizes[1] / 2;        // 1600000

    char* w = (char*)d_ws;
    size_t off = 0;
    auto alloc = [&](size_t bytes) -> char* {
        char* p = w + off;
        off += (bytes + 255) & ~(size_t)255;
        return p;
    };
    int*   cnt    = (int*)  alloc((size_t)N * 4);
    int*   fillc  = (int*)  alloc((size_t)N * 4);   // adjacent to cnt: one memset
    int*   offs   = (int*)  alloc((size_t)(N + 1) * 4);
    float* dinv   = (float*)alloc((size_t)MPAD * 4); // padded: epilogues read r<MPAD
    int*   flag   = (int*)  alloc(256);
    int*   rowidx = (int*)  alloc((size_t)E * 4);    // no memset needed: every slot written
    unsigned short* Bt1 = (unsigned short*)alloc((size_t)HID * KP1 * 2);
    unsigned short* Bt2 = (unsigned short*)alloc((size_t)HID * HID * 2);
    unsigned short* Bt3 = (unsigned short*)alloc((size_t)NP3 * HID * 2);
    unsigned short* bufA = (unsigned short*)alloc((size_t)MPAD * HID * 2);
    unsigned short* bufB = (unsigned short*)alloc((size_t)MPAD * HID * 2);
    unsigned short* Xs  = bufA;    // padx out
    unsigned short* Y1  = bufB;    // aggx out
    unsigned short* H1s = bufA;    // gemm1 out (Xs dead)
    unsigned short* Y2  = bufB;    // agg256c out (Y1 dead)
    unsigned short* G3  = bufA;    // mlp23 out (H1s dead)

    // one memset covers cnt + pad + fillc (contiguous in ws)
    size_t msz = (size_t)((char*)fillc - (char*)cnt) + (size_t)N * 4;
    hipMemsetAsync(cnt, 0, msz, stream);

    k_detect<<<1, 64, 0, stream>>>(ei, flag, N);
    k_count<<<(E + 255) / 256, 256, 0, stream>>>(ei, flag, cnt, E, N);
    k_scan<<<1, 1024, 0, stream>>>(cnt, offs, dinv, N);
    k_fill<<<(E + 255) / 256, 256, 0, stream>>>(ei, flag, offs, fillc, rowidx, E, N);

    int prep_grid = (N * KP1 + 255) / 256 + (HID * KP1) / 256 + (HID * HID) / 256 + (NP3 * HID) / 256;
    k_prep<<<prep_grid, 256, 0, stream>>>(x, dinv, Xs, W1, Bt1, W2, Bt2, W3, Bt3, N);

    // layer 1: aggregate-first, then GEMM (+b1, relu, *dinv)
    k_aggx<<<(N + 31) / 32, 256, 0, stream>>>(Xs, offs, rowidx, dinv, Y1, N);
    dim3 g1(MPAD / 128, HID / 128);
    k_gemm_lds<<<g1, 256, 0, stream>>>(Y1, Bt1, dinv, b1, H1s, KP1, HID, 1, 1, 1);
    // layer 2 aggregate (64B chunks), then fused GEMM2+GEMM3
    int bpc2 = (N + 63) / 64;
    k_agg256c<<<8 * bpc2, 256, 0, stream>>>(H1s, offs, rowidx, dinv, Y2, N);
    k_mlp23<<<MPAD / 128, 256, 0, stream>>>(Y2, Bt2, Bt3, b2, dinv, G3);
    // layer 3 aggregate (+b3), f32 out
    int half_n = (N + 1) / 2;
    int bpc3 = (half_n + 63) / 64;
    k_aggouts64<<<8 * bpc3, 256, 0, stream>>>(G3, offs, rowidx, dinv, b3, out, N, half_n);

    (void)n_in; (void)out_size; (void)ws_size;
}

// Round 5
// 656.905 us; speedup vs baseline: 1.2708x; 1.2708x over previous
//
#include <hip/hip_runtime.h>

// GCN 3-layer forward on MI355X.
// Pipeline (A_hat (X W) = (A_hat X) W):
//   aggx:  Y1 = A_hat X          GEMM1: H1s = dinv*relu(Y1 W1 + b1)
//   agg256s: Y2 = A_hat H1       MLP23: G3 = dinv*((relu(Y2 W2 + b2)) W3)  [fused]
//   aggouts: out = dinv[c]*(sum G3[r]+G3[c]) + b3 (f32)
// Gather wall (r0-r4 measured): L2-fill path ~3.6-3.8 TB/s; FETCH bytes are the
// lever. Fetch granule = 128B (r4 falsified 64B: FETCH doubled). Proven geometry
// (r3): feature-split in 128B chunks, chunk+dest-split -> XCD cell via bid&7.
//   agg256s: 4 chunks x 2 halves (slab 12.8MB/XCD, ~40% miss, FETCH ~329MB)
//   aggouts: 2 chunks x 4 quarters (slab 3.2MB/XCD -- fits L2)
// MLP23 fusion: H2 tile (128x256 bf16, 64KB) stays in LDS (XOR-swizzle
// (row&7)<<4 on write+read); W3 (64KB, L2-resident) read direct in phase 2.
// CSR build: atomics only on memset-initialized arrays; rowidx needs no memset
// (every slot [0,E) written exactly once); rowidx clamped at read.

#define IN_F 50
#define HID  256
#define OUT_F 121
#define KP1  64      // layer-1 width padded 50->64
#define NP3  128     // layer-3 N padded 121->128
#define MPAD 100096  // 782 * 128

typedef __attribute__((ext_vector_type(8))) short bf16x8;
typedef __attribute__((ext_vector_type(4))) float f32x4;

__device__ __forceinline__ float bf2f(unsigned short u) {
    union { unsigned int i; float f; } x; x.i = ((unsigned int)u) << 16; return x.f;
}
__device__ __forceinline__ unsigned short f2bf(float f) {
    union { float f; unsigned int i; } x; x.f = f;
    unsigned int r = x.i + 0x7FFFu + ((x.i >> 16) & 1u);  // RNE
    return (unsigned short)(r >> 16);
}

__device__ __forceinline__ void gl2lds16(const void* g, void* l) {
    __builtin_amdgcn_global_load_lds(
        (const __attribute__((address_space(1))) void*)g,
        (__attribute__((address_space(3))) void*)l, 16, 0, 0);
}

// ---- edge dtype detection (int64 vs int32), 64-lane parallel ----------------
__global__ void k_detect(const int* __restrict__ ei, int* __restrict__ flag, int N) {
    int i = threadIdx.x;
    int lo = ei[2 * i], hi = ei[2 * i + 1];
    int bad = (hi != 0) || ((unsigned)lo >= (unsigned)N);
    unsigned long long m = __ballot(bad);
    if (threadIdx.x == 0) *flag = (m == 0ULL) ? 1 : 0;
}

// ---- CSR build --------------------------------------------------------------

__global__ void k_count(const int* __restrict__ ei, const int* __restrict__ flag,
                        int* __restrict__ cnt, int E, int N) {
    int t = blockIdx.x * blockDim.x + threadIdx.x;
    if (t >= E) return;
    int f = *flag;
    int c = f ? ei[2 * (E + t)] : ei[E + t];
    c = min(max(c, 0), N - 1);
    atomicAdd(&cnt[c], 1);
}

__global__ __launch_bounds__(1024) void k_scan(const int* __restrict__ cnt,
                                               int* __restrict__ offs,
                                               float* __restrict__ dinv, int n) {
    __shared__ int wsum[16];
    __shared__ int s_carry;
    int lane = threadIdx.x & 63, wid = threadIdx.x >> 6;
    if (threadIdx.x == 0) s_carry = 0;
    __syncthreads();
    for (int base = 0; base < n; base += 4096) {
        int i0 = base + (int)threadIdx.x * 4;
        int v0 = (i0 + 0 < n) ? cnt[i0 + 0] : 0;
        int v1 = (i0 + 1 < n) ? cnt[i0 + 1] : 0;
        int v2 = (i0 + 2 < n) ? cnt[i0 + 2] : 0;
        int v3 = (i0 + 3 < n) ? cnt[i0 + 3] : 0;
        int s1 = v0 + v1, s2 = s1 + v2, tsum = s2 + v3;
        int x = tsum;
        #pragma unroll
        for (int d = 1; d < 64; d <<= 1) {
            int y = __shfl_up(x, d, 64);
            if (lane >= d) x += y;
        }
        if (lane == 63) wsum[wid] = x;
        __syncthreads();
        int wpre = 0;
        #pragma unroll
        for (int j = 0; j < 16; j++) wpre += (j < wid) ? wsum[j] : 0;
        int carry = s_carry;
        int e0 = carry + wpre + x - tsum;
        if (i0 + 0 < n) { offs[i0+0]=e0;    dinv[i0+0]=rsqrtf((float)(v0+1)); }
        if (i0 + 1 < n) { offs[i0+1]=e0+v0; dinv[i0+1]=rsqrtf((float)(v1+1)); }
        if (i0 + 2 < n) { offs[i0+2]=e0+s1; dinv[i0+2]=rsqrtf((float)(v2+1)); }
        if (i0 + 3 < n) { offs[i0+3]=e0+s2; dinv[i0+3]=rsqrtf((float)(v3+1)); }
        __syncthreads();
        if (threadIdx.x == 1023) s_carry = carry + wpre + x;
        __syncthreads();
    }
    if (threadIdx.x == 0) offs[n] = s_carry;
}

__global__ void k_fill(const int* __restrict__ ei, const int* __restrict__ flag,
                       const int* __restrict__ offs,
                       int* __restrict__ fillc, int* __restrict__ rowidx, int E, int N) {
    int t = blockIdx.x * blockDim.x + threadIdx.x;
    if (t >= E) return;
    int f = *flag;
    int c = f ? ei[2 * (E + t)] : ei[E + t];
    int r = f ? ei[2 * t] : ei[t];
    c = min(max(c, 0), N - 1);
    r = min(max(r, 0), N - 1);
    int pos = offs[c] + atomicAdd(&fillc[c], 1);
    if ((unsigned)pos < (unsigned)E) rowidx[pos] = r;
}

// ---- input prep (padx + 3 weight transposes, one launch) --------------------
__global__ void k_prep(const float* __restrict__ x, const float* __restrict__ dinv,
                       unsigned short* __restrict__ Xs,
                       const float* __restrict__ W1, unsigned short* __restrict__ Bt1,
                       const float* __restrict__ W2, unsigned short* __restrict__ Bt2,
                       const float* __restrict__ W3, unsigned short* __restrict__ Bt3,
                       int N) {
    int bid = blockIdx.x;
    int npadx = (N * KP1 + 255) / 256;
    if (bid < npadx) {
        int idx = bid * 256 + (int)threadIdx.x;
        if (idx < N * KP1) {
            int node = idx >> 6, k = idx & 63;
            Xs[idx] = (k < IN_F) ? f2bf(dinv[node] * x[node * IN_F + k]) : (unsigned short)0;
        }
        return;
    }
    bid -= npadx;
    if (bid < (HID * KP1) / 256) {          // Bt1 [256][64]
        int idx = bid * 256 + (int)threadIdx.x;
        int nn = idx >> 6, k = idx & 63;
        Bt1[idx] = (k < IN_F) ? f2bf(W1[k * HID + nn]) : (unsigned short)0;
        return;
    }
    bid -= (HID * KP1) / 256;
    if (bid < (HID * HID) / 256) {          // Bt2 [256][256]
        int idx = bid * 256 + (int)threadIdx.x;
        int nn = idx >> 8, k = idx & 255;
        Bt2[idx] = f2bf(W2[k * HID + nn]);
        return;
    }
    bid -= (HID * HID) / 256;
    {                                        // Bt3 [128][256]
        int idx = bid * 256 + (int)threadIdx.x;
        int nn = idx >> 8, k = idx & 255;
        Bt3[idx] = (nn < OUT_F) ? f2bf(W3[k * OUT_F + nn]) : (unsigned short)0;
    }
}

// ---- LDS-tiled GEMM (m97 structure) — layer 1 only --------------------------
__global__ __launch_bounds__(256) void k_gemm_lds(const unsigned short* __restrict__ A,
                                                  const unsigned short* __restrict__ Bt,
                                                  const float* __restrict__ dinv,
                                                  const float* __restrict__ bias,
                                                  unsigned short* __restrict__ C,
                                                  int K, int Nout,
                                                  int BIAS, int RELU, int SCALE) {
    __shared__ char lds[16384];   // A tile [128][32] bf16 @0, B tile @8192
    const int tid = threadIdx.x;
    const int wid = tid >> 6, lane = tid & 63;
    const int wm = wid & 1, wn = wid >> 1;
    const int quad = lane >> 4, ml = lane & 15;
    const int m0 = blockIdx.x * 128;
    const int n0g = blockIdx.y * 128;

    f32x4 acc[4][4];
    #pragma unroll
    for (int a = 0; a < 4; a++)
        #pragma unroll
        for (int b = 0; b < 4; b++) acc[a][b] = (f32x4){0.f, 0.f, 0.f, 0.f};

    for (int kk = 0; kk < K; kk += 32) {
        #pragma unroll
        for (int r = 0; r < 2; r++) {
            int c = r * 256 + tid;
            int row = c >> 2, q = c & 3;
            gl2lds16(A  + (size_t)(m0  + row) * K + kk + q * 8, lds + c * 16);
            gl2lds16(Bt + (size_t)(n0g + row) * K + kk + q * 8, lds + 8192 + c * 16);
        }
        __syncthreads();
        bf16x8 af[4], bfv[4];
        #pragma unroll
        for (int mf = 0; mf < 4; mf++)
            af[mf] = *(const bf16x8*)(lds + ((wm * 64 + mf * 16 + ml) * 64 + quad * 16));
        #pragma unroll
        for (int nf = 0; nf < 4; nf++)
            bfv[nf] = *(const bf16x8*)(lds + 8192 + ((wn * 64 + nf * 16 + ml) * 64 + quad * 16));
        #pragma unroll
        for (int mf = 0; mf < 4; mf++)
            #pragma unroll
            for (int nf = 0; nf < 4; nf++)
                acc[mf][nf] = __builtin_amdgcn_mfma_f32_16x16x32_bf16(af[mf], bfv[nf], acc[mf][nf], 0, 0, 0);
        __syncthreads();
    }

    #pragma unroll
    for (int mf = 0; mf < 4; mf++) {
        int r0 = m0 + wm * 64 + mf * 16 + quad * 4;
        float dd[4] = {1.f, 1.f, 1.f, 1.f};
        if (SCALE) { dd[0]=dinv[r0]; dd[1]=dinv[r0+1]; dd[2]=dinv[r0+2]; dd[3]=dinv[r0+3]; }
        #pragma unroll
        for (int nf = 0; nf < 4; nf++) {
            int col = n0g + wn * 64 + nf * 16 + ml;
            float bb = BIAS ? bias[col] : 0.f;
            #pragma unroll
            for (int i = 0; i < 4; i++) {
                float v = acc[mf][nf][i] + bb;
                if (RELU) v = fmaxf(v, 0.f);
                v *= dd[i];
                C[(size_t)(r0 + i) * Nout + col] = f2bf(v);
            }
        }
    }
}

// ---- FUSED GEMM2+GEMM3: G3 = dinv * (relu(Y2 W2 + b2) W3) -------------------
__global__ __launch_bounds__(256) void k_mlp23(const unsigned short* __restrict__ A,
                                               const unsigned short* __restrict__ B2t,
                                               const unsigned short* __restrict__ B3t,
                                               const float* __restrict__ b2,
                                               const float* __restrict__ dinv,
                                               unsigned short* __restrict__ G) {
    __shared__ char lds[65536];  // phase1 staging: A[128][32]@0, B2[256][32]@8192 (24KB)
                                 // then H2 [128][256] bf16 @0 (64KB, swizzled)
    const int tid = threadIdx.x;
    const int wid = tid >> 6, lane = tid & 63;
    const int wm = wid & 1, wn = wid >> 1;
    const int quad = lane >> 4, ml = lane & 15;
    const int m0 = blockIdx.x * 128;

    f32x4 acc1[4][8];
    #pragma unroll
    for (int a = 0; a < 4; a++)
        #pragma unroll
        for (int b = 0; b < 8; b++) acc1[a][b] = (f32x4){0.f, 0.f, 0.f, 0.f};

    for (int kk = 0; kk < HID; kk += 32) {
        #pragma unroll
        for (int r = 0; r < 2; r++) {
            int c = r * 256 + tid;
            int row = c >> 2, q = c & 3;
            gl2lds16(A + (size_t)(m0 + row) * HID + kk + q * 8, lds + c * 16);
        }
        #pragma unroll
        for (int r = 0; r < 4; r++) {
            int c = r * 256 + tid;
            int nn = c >> 2, q = c & 3;
            gl2lds16(B2t + (size_t)nn * HID + kk + q * 8, lds + 8192 + c * 16);
        }
        __syncthreads();
        bf16x8 af[4], bv[8];
        #pragma unroll
        for (int mf = 0; mf < 4; mf++)
            af[mf] = *(const bf16x8*)(lds + ((wm * 64 + mf * 16 + ml) * 64 + quad * 16));
        #pragma unroll
        for (int nf = 0; nf < 8; nf++)
            bv[nf] = *(const bf16x8*)(lds + 8192 + ((wn * 128 + nf * 16 + ml) * 64 + quad * 16));
        #pragma unroll
        for (int mf = 0; mf < 4; mf++)
            #pragma unroll
            for (int nf = 0; nf < 8; nf++)
                acc1[mf][nf] = __builtin_amdgcn_mfma_f32_16x16x32_bf16(af[mf], bv[nf], acc1[mf][nf], 0, 0, 0);
        __syncthreads();
    }

    // H2 = relu(acc1 + b2) -> LDS bf16, swizzled byte ^= (row&7)<<4
    #pragma unroll
    for (int nf = 0; nf < 8; nf++) {
        int col = wn * 128 + nf * 16 + ml;
        float bb = b2[col];
        #pragma unroll
        for (int mf = 0; mf < 4; mf++) {
            int rl = wm * 64 + mf * 16 + quad * 4;
            #pragma unroll
            for (int i = 0; i < 4; i++) {
                int row = rl + i;
                int byte = (row * 512 + col * 2) ^ ((row & 7) << 4);
                *(unsigned short*)(lds + byte) = f2bf(fmaxf(acc1[mf][nf][i] + bb, 0.f));
            }
        }
    }
    __syncthreads();

    // phase 2: G3 tile (128x128), A from H2-LDS, B direct from global Bt3
    f32x4 acc2[4][4];
    #pragma unroll
    for (int a = 0; a < 4; a++)
        #pragma unroll
        for (int b = 0; b < 4; b++) acc2[a][b] = (f32x4){0.f, 0.f, 0.f, 0.f};

    for (int kk = 0; kk < HID; kk += 32) {
        bf16x8 af2[4], bv2[4];
        #pragma unroll
        for (int mf = 0; mf < 4; mf++) {
            int row = wm * 64 + mf * 16 + ml;
            int byte = (row * 512 + kk * 2 + quad * 16) ^ ((row & 7) << 4);
            af2[mf] = *(const bf16x8*)(lds + byte);
        }
        #pragma unroll
        for (int nf = 0; nf < 4; nf++)
            bv2[nf] = *(const bf16x8*)(B3t + (size_t)(wn * 64 + nf * 16 + ml) * HID + kk + quad * 8);
        #pragma unroll
        for (int mf = 0; mf < 4; mf++)
            #pragma unroll
            for (int nf = 0; nf < 4; nf++)
                acc2[mf][nf] = __builtin_amdgcn_mfma_f32_16x16x32_bf16(af2[mf], bv2[nf], acc2[mf][nf], 0, 0, 0);
    }

    #pragma unroll
    for (int mf = 0; mf < 4; mf++) {
        int r0 = m0 + wm * 64 + mf * 16 + quad * 4;
        float dd[4] = {dinv[r0], dinv[r0+1], dinv[r0+2], dinv[r0+3]};
        #pragma unroll
        for (int nf = 0; nf < 4; nf++) {
            int col = wn * 64 + nf * 16 + ml;
            #pragma unroll
            for (int i = 0; i < 4; i++)
                G[(size_t)(r0 + i) * NP3 + col] = f2bf(acc2[mf][nf][i] * dd[i]);
        }
    }
}

// ---- aggregation kernels ----------------------------------------------------
// 16B/lane gathers, masked unroll-4 edge loop (tail lanes re-read last edge row
// -> L1 hit; fma-masked with 0).

__device__ __forceinline__ int rclamp(int r, int N) { return min(max(r, 0), N - 1); }

// aggx: rows 64 bf16 = 128B (1 line, no split) -> 8 lanes/row, 8 nodes/wave.
__global__ void k_aggx(const unsigned short* __restrict__ Xs,
                       const int* __restrict__ offs, const int* __restrict__ rowidx,
                       const float* __restrict__ dinv, unsigned short* __restrict__ Y, int N) {
    int wid = threadIdx.x >> 6, lane = threadIdx.x & 63;
    int sub = lane >> 3, sl = lane & 7;
    int node = blockIdx.x * 32 + wid * 8 + sub;
    int nc = min(node, N - 1);
    int c = sl * 8;
    bf16x8 s = *(const bf16x8*)(Xs + (size_t)nc * KP1 + c);
    float a[8];
    #pragma unroll
    for (int k = 0; k < 8; k++) a[k] = bf2f((unsigned short)s[k]);
    int e = offs[nc], end = offs[nc + 1];
    if (node >= N) { e = 0; end = 0; }
    while (__any(e < end)) {
        int r[4]; float m[4];
        #pragma unroll
        for (int j = 0; j < 4; j++) {
            int idx = e + j;
            m[j] = (idx < end) ? 1.f : 0.f;
            idx = min(idx, end - 1); idx = max(idx, 0);
            r[j] = rclamp(rowidx[idx], N);
        }
        bf16x8 u[4];
        #pragma unroll
        for (int j = 0; j < 4; j++)
            u[j] = *(const bf16x8*)(Xs + (size_t)r[j] * KP1 + c);
        #pragma unroll
        for (int j = 0; j < 4; j++)
            #pragma unroll
            for (int k = 0; k < 8; k++)
                a[k] = fmaf(bf2f((unsigned short)u[j][k]), m[j], a[k]);
        e += 4;
    }
    if (node < N) {
        float dv = dinv[node];
        bf16x8 o;
        #pragma unroll
        for (int k = 0; k < 8; k++) o[k] = (short)f2bf(a[k] * dv);
        *(bf16x8*)(Y + (size_t)node * KP1 + c) = o;
    }
}

// agg256s: FEATURE-SPLIT gather, 256-wide rows. 4 chunks of 64 bf16 (128B line);
// cell = bid&7: chunk = cell>>1, dest-half = cell&1. 8 lanes/chunk-row,
// 8 nodes/wave, 32/block. Per-XCD slab 12.8MB (r3-proven: FETCH ~329MB, 107us).
__global__ void k_agg256s(const unsigned short* __restrict__ Hn,
                          const int* __restrict__ offs, const int* __restrict__ rowidx,
                          const float* __restrict__ dinv, unsigned short* __restrict__ Y,
                          int N, int half_n) {
    int cell = blockIdx.x & 7;
    int chunk = cell >> 1, half = cell & 1;
    int idx = blockIdx.x >> 3;
    int wid = threadIdx.x >> 6, lane = threadIdx.x & 63;
    int sub = lane >> 3, sl = lane & 7;
    int node = half * half_n + idx * 32 + wid * 8 + sub;
    int hi_end = min((half + 1) * half_n, N);
    int ok = node < hi_end;
    int nc = ok ? node : hi_end - 1;
    int c = chunk * 64 + sl * 8;
    bf16x8 s = *(const bf16x8*)(Hn + (size_t)nc * HID + c);
    float a[8];
    #pragma unroll
    for (int k = 0; k < 8; k++) a[k] = bf2f((unsigned short)s[k]);
    int e = offs[nc], end = offs[nc + 1];
    if (!ok) { e = 0; end = 0; }
    while (__any(e < end)) {
        int r[4]; float m[4];
        #pragma unroll
        for (int j = 0; j < 4; j++) {
            int idx2 = e + j;
            m[j] = (idx2 < end) ? 1.f : 0.f;
            idx2 = min(idx2, end - 1); idx2 = max(idx2, 0);
            r[j] = rclamp(rowidx[idx2], N);
        }
        bf16x8 u[4];
        #pragma unroll
        for (int j = 0; j < 4; j++)
            u[j] = *(const bf16x8*)(Hn + (size_t)r[j] * HID + c);
        #pragma unroll
        for (int j = 0; j < 4; j++)
            #pragma unroll
            for (int k = 0; k < 8; k++)
                a[k] = fmaf(bf2f((unsigned short)u[j][k]), m[j], a[k]);
        e += 4;
    }
    if (ok) {
        float dv = dinv[node];
        bf16x8 o;
        #pragma unroll
        for (int k = 0; k < 8; k++) o[k] = (short)f2bf(a[k] * dv);
        *(bf16x8*)(Y + (size_t)node * HID + c) = o;
    }
}

// aggouts: FEATURE-SPLIT gather, 128-wide rows. 2 chunks of 64 bf16 (128B line)
// x 4 dest-quarters; cell = bid&7: chunk = cell>>2, quarter = cell&3.
// Per-XCD slab 3.2MB -- fits L2 (r3-proven).
__global__ void k_aggouts(const unsigned short* __restrict__ G,
                          const int* __restrict__ offs, const int* __restrict__ rowidx,
                          const float* __restrict__ dinv, const float* __restrict__ bias,
                          float* __restrict__ out, int N, int quar_n) {
    int cell = blockIdx.x & 7;
    int chunk = cell >> 2, quar = cell & 3;
    int idx = blockIdx.x >> 3;
    int wid = threadIdx.x >> 6, lane = threadIdx.x & 63;
    int sub = lane >> 3, sl = lane & 7;
    int node = quar * quar_n + idx * 32 + wid * 8 + sub;
    int hi_end = min((quar + 1) * quar_n, N);
    int ok = node < hi_end;
    int nc = ok ? node : hi_end - 1;
    int c = chunk * 64 + sl * 8;
    bf16x8 s = *(const bf16x8*)(G + (size_t)nc * NP3 + c);
    float a[8];
    #pragma unroll
    for (int k = 0; k < 8; k++) a[k] = bf2f((unsigned short)s[k]);
    int e = offs[nc], end = offs[nc + 1];
    if (!ok) { e = 0; end = 0; }
    while (__any(e < end)) {
        int r[4]; float m[4];
        #pragma unroll
        for (int j = 0; j < 4; j++) {
            int idx2 = e + j;
            m[j] = (idx2 < end) ? 1.f : 0.f;
            idx2 = min(idx2, end - 1); idx2 = max(idx2, 0);
            r[j] = rclamp(rowidx[idx2], N);
        }
        bf16x8 u[4];
        #pragma unroll
        for (int j = 0; j < 4; j++)
            u[j] = *(const bf16x8*)(G + (size_t)r[j] * NP3 + c);
        #pragma unroll
        for (int j = 0; j < 4; j++)
            #pragma unroll
            for (int k = 0; k < 8; k++)
                a[k] = fmaf(bf2f((unsigned short)u[j][k]), m[j], a[k]);
        e += 4;
    }
    if (ok) {
        float dv = dinv[node];
        #pragma unroll
        for (int k = 0; k < 8; k++) {
            int col = c + k;
            if (col < OUT_F)
                out[(size_t)node * OUT_F + col] = fmaf(a[k], dv, bias[col]);
        }
    }
}

// ---- launch -----------------------------------------------------------------

extern "C" void kernel_launch(void* const* d_in, const int* in_sizes, int n_in,
                              void* d_out, int out_size, void* d_ws, size_t ws_size,
                              hipStream_t stream) {
    const float* x  = (const float*)d_in[0];
    const int*   ei = (const int*)d_in[1];
    const float* W1 = (const float*)d_in[2];
    const float* b1 = (const float*)d_in[3];
    const float* W2 = (const float*)d_in[4];
    const float* b2 = (const float*)d_in[5];
    const float* W3 = (const float*)d_in[6];
    const float* b3 = (const float*)d_in[7];
    float* out = (float*)d_out;

    const int N = in_sizes[0] / IN_F;     // 100000
    const int E = in_sizes[1] / 2;        // 1600000

    char* w = (char*)d_ws;
    size_t off = 0;
    auto alloc = [&](size_t bytes) -> char* {
        char* p = w + off;
        off += (bytes + 255) & ~(size_t)255;
        return p;
    };
    int*   cnt    = (int*)  alloc((size_t)N * 4);
    int*   fillc  = (int*)  alloc((size_t)N * 4);   // adjacent to cnt: one memset
    int*   offs   = (int*)  alloc((size_t)(N + 1) * 4);
    float* dinv   = (float*)alloc((size_t)MPAD * 4); // padded: epilogues read r<MPAD
    int*   flag   = (int*)  alloc(256);
    int*   rowidx = (int*)  alloc((size_t)E * 4);    // no memset: every slot written
    unsigned short* Bt1 = (unsigned short*)alloc((size_t)HID * KP1 * 2);
    unsigned short* Bt2 = (unsigned short*)alloc((size_t)HID * HID * 2);
    unsigned short* Bt3 = (unsigned short*)alloc((size_t)NP3 * HID * 2);
    unsigned short* bufA = (unsigned short*)alloc((size_t)MPAD * HID * 2);
    unsigned short* bufB = (unsigned short*)alloc((size_t)MPAD * HID * 2);
    unsigned short* Xs  = bufA;    // prep out
    unsigned short* Y1  = bufB;    // aggx out
    unsigned short* H1s = bufA;    // gemm1 out (Xs dead)
    unsigned short* Y2  = bufB;    // agg256s out (Y1 dead)
    unsigned short* G3  = bufA;    // mlp23 out (H1s dead)

    // one memset covers cnt + pad + fillc (contiguous in ws)
    size_t msz = (size_t)((char*)fillc - (char*)cnt) + (size_t)N * 4;
    hipMemsetAsync(cnt, 0, msz, stream);

    k_detect<<<1, 64, 0, stream>>>(ei, flag, N);
    k_count<<<(E + 255) / 256, 256, 0, stream>>>(ei, flag, cnt, E, N);
    k_scan<<<1, 1024, 0, stream>>>(cnt, offs, dinv, N);
    k_fill<<<(E + 255) / 256, 256, 0, stream>>>(ei, flag, offs, fillc, rowidx, E, N);

    int prep_grid = (N * KP1 + 255) / 256 + (HID * KP1) / 256 + (HID * HID) / 256 + (NP3 * HID) / 256;
    k_prep<<<prep_grid, 256, 0, stream>>>(x, dinv, Xs, W1, Bt1, W2, Bt2, W3, Bt3, N);

    // layer 1: aggregate-first, then GEMM (+b1, relu, *dinv)
    k_aggx<<<(N + 31) / 32, 256, 0, stream>>>(Xs, offs, rowidx, dinv, Y1, N);
    dim3 g1(MPAD / 128, HID / 128);
    k_gemm_lds<<<g1, 256, 0, stream>>>(Y1, Bt1, dinv, b1, H1s, KP1, HID, 1, 1, 1);
    // layer 2 aggregate (128B chunks, 4x2), then fused GEMM2+GEMM3
    int half_n = (N + 1) / 2;
    int bpc2 = (half_n + 31) / 32;
    k_agg256s<<<8 * bpc2, 256, 0, stream>>>(H1s, offs, rowidx, dinv, Y2, N, half_n);
    k_mlp23<<<MPAD / 128, 256, 0, stream>>>(Y2, Bt2, Bt3, b2, dinv, G3);
    // layer 3 aggregate (+b3), f32 out (128B chunks, 2x4)
    int quar_n = (N + 3) / 4;
    int bpc3 = (quar_n + 31) / 32;
    k_aggouts<<<8 * bpc3, 256, 0, stream>>>(G3, offs, rowidx, dinv, b3, out, N, quar_n);

    (void)n_in; (void)out_size; (void)ws_size;
}

// Round 6
// 621.612 us; speedup vs baseline: 1.3429x; 1.0568x over previous
//
#include <hip/hip_runtime.h>

// GCN 3-layer forward on MI355X.
// Pipeline (A_hat (X W) = (A_hat X) W):
//   aggx:  Y1 = A_hat X          GEMM1: H1s = dinv*relu(Y1 W1 + b1)
//   agg256s: Y2 = A_hat H1       MLP23: G3 = dinv*((relu(Y2 W2 + b2)) W3)  [fused]
//   aggouts: out = dinv[c]*(sum G3[r]+G3[c]) + b3 (f32)
// Gather wall (r0-r4): L2-fill path ~3.6-3.8 TB/s; FETCH bytes are the lever.
// Fetch granule = 128B (r4 falsified 64B). Proven geometry (r3): feature-split
// in 128B chunks, chunk+dest-split -> XCD cell via bid&7.
//   agg256s: 4 chunks x 2 halves (slab 12.8MB/XCD, FETCH ~329MB)
//   aggouts: 2 chunks x 4 quarters (slab 3.2MB/XCD -- fits L2)
// NEW r6: k_fill8 -- CSR fill with XCD-range-split WRITES. r5 counters showed
// k_fill at 120us with WRITE_SIZE 107MB for a 6.4MB payload (17x partial-line
// write amplification: all 8 non-coherent L2s interleave 4B scatters into the
// same lines). Fix: cell = bid&7 owns dest-range [cell*N/8, ...); each cell
// scans all edges, commits only its range -> each rowidx region written by ONE
// XCD -> L2 accumulates full lines -> writeback ~= compulsory 6.4MB. Streaming
// re-read of edge cols (8 x 12.8MB) is cheap vs the removed write thrash.
// rowidx order within a node was already nondeterministic (atomic rank);
// absmax bit-stable at 2^-10 across 5 rounds -> reorder-safe.
// MLP23 fusion: H2 tile (128x256 bf16, 64KB) stays in LDS (XOR-swizzle
// (row&7)<<4 on write+read); W3 (64KB, L2-resident) read direct in phase 2.

#define IN_F 50
#define HID  256
#define OUT_F 121
#define KP1  64      // layer-1 width padded 50->64
#define NP3  128     // layer-3 N padded 121->128
#define MPAD 100096  // 782 * 128

typedef __attribute__((ext_vector_type(8))) short bf16x8;
typedef __attribute__((ext_vector_type(4))) float f32x4;

__device__ __forceinline__ float bf2f(unsigned short u) {
    union { unsigned int i; float f; } x; x.i = ((unsigned int)u) << 16; return x.f;
}
__device__ __forceinline__ unsigned short f2bf(float f) {
    union { float f; unsigned int i; } x; x.f = f;
    unsigned int r = x.i + 0x7FFFu + ((x.i >> 16) & 1u);  // RNE
    return (unsigned short)(r >> 16);
}

__device__ __forceinline__ void gl2lds16(const void* g, void* l) {
    __builtin_amdgcn_global_load_lds(
        (const __attribute__((address_space(1))) void*)g,
        (__attribute__((address_space(3))) void*)l, 16, 0, 0);
}

// ---- edge dtype detection (int64 vs int32), 64-lane parallel ----------------
__global__ void k_detect(const int* __restrict__ ei, int* __restrict__ flag, int N) {
    int i = threadIdx.x;
    int lo = ei[2 * i], hi = ei[2 * i + 1];
    int bad = (hi != 0) || ((unsigned)lo >= (unsigned)N);
    unsigned long long m = __ballot(bad);
    if (threadIdx.x == 0) *flag = (m == 0ULL) ? 1 : 0;
}

// ---- CSR build --------------------------------------------------------------

__global__ void k_count(const int* __restrict__ ei, const int* __restrict__ flag,
                        int* __restrict__ cnt, int E, int N) {
    int t = blockIdx.x * blockDim.x + threadIdx.x;
    if (t >= E) return;
    int f = *flag;
    int c = f ? ei[2 * (E + t)] : ei[E + t];
    c = min(max(c, 0), N - 1);
    atomicAdd(&cnt[c], 1);
}

__global__ __launch_bounds__(1024) void k_scan(const int* __restrict__ cnt,
                                               int* __restrict__ offs,
                                               float* __restrict__ dinv, int n) {
    __shared__ int wsum[16];
    __shared__ int s_carry;
    int lane = threadIdx.x & 63, wid = threadIdx.x >> 6;
    if (threadIdx.x == 0) s_carry = 0;
    __syncthreads();
    for (int base = 0; base < n; base += 4096) {
        int i0 = base + (int)threadIdx.x * 4;
        int v0 = (i0 + 0 < n) ? cnt[i0 + 0] : 0;
        int v1 = (i0 + 1 < n) ? cnt[i0 + 1] : 0;
        int v2 = (i0 + 2 < n) ? cnt[i0 + 2] : 0;
        int v3 = (i0 + 3 < n) ? cnt[i0 + 3] : 0;
        int s1 = v0 + v1, s2 = s1 + v2, tsum = s2 + v3;
        int x = tsum;
        #pragma unroll
        for (int d = 1; d < 64; d <<= 1) {
            int y = __shfl_up(x, d, 64);
            if (lane >= d) x += y;
        }
        if (lane == 63) wsum[wid] = x;
        __syncthreads();
        int wpre = 0;
        #pragma unroll
        for (int j = 0; j < 16; j++) wpre += (j < wid) ? wsum[j] : 0;
        int carry = s_carry;
        int e0 = carry + wpre + x - tsum;
        if (i0 + 0 < n) { offs[i0+0]=e0;    dinv[i0+0]=rsqrtf((float)(v0+1)); }
        if (i0 + 1 < n) { offs[i0+1]=e0+v0; dinv[i0+1]=rsqrtf((float)(v1+1)); }
        if (i0 + 2 < n) { offs[i0+2]=e0+s1; dinv[i0+2]=rsqrtf((float)(v2+1)); }
        if (i0 + 3 < n) { offs[i0+3]=e0+s2; dinv[i0+3]=rsqrtf((float)(v3+1)); }
        __syncthreads();
        if (threadIdx.x == 1023) s_carry = carry + wpre + x;
        __syncthreads();
    }
    if (threadIdx.x == 0) offs[n] = s_carry;
}

// k_fill8: XCD-range-split CSR fill. cell = bid&7 -> XCD (round-robin mapping,
// r3/r5-validated); cell owns dest range [cell*rng, min((cell+1)*rng, N)).
// Each cell scans all E edges, commits only its range: rowidx region written
// by one XCD only -> full-line writeback (~6.4MB vs r5's 107MB).
__global__ void k_fill8(const int* __restrict__ ei, const int* __restrict__ flag,
                        const int* __restrict__ offs,
                        int* __restrict__ fillc, int* __restrict__ rowidx,
                        int E, int N, int rng) {
    int cell = blockIdx.x & 7;
    int t = (blockIdx.x >> 3) * blockDim.x + threadIdx.x;
    if (t >= E) return;
    int f = *flag;
    int c = f ? ei[2 * (E + t)] : ei[E + t];
    c = min(max(c, 0), N - 1);
    int lo = cell * rng;
    int hi = min(lo + rng, N);
    if (c < lo || c >= hi) return;
    int r = f ? ei[2 * t] : ei[t];
    r = min(max(r, 0), N - 1);
    int pos = offs[c] + atomicAdd(&fillc[c], 1);
    if ((unsigned)pos < (unsigned)E) rowidx[pos] = r;
}

// ---- input prep (padx + 3 weight transposes, one launch) --------------------
__global__ void k_prep(const float* __restrict__ x, const float* __restrict__ dinv,
                       unsigned short* __restrict__ Xs,
                       const float* __restrict__ W1, unsigned short* __restrict__ Bt1,
                       const float* __restrict__ W2, unsigned short* __restrict__ Bt2,
                       const float* __restrict__ W3, unsigned short* __restrict__ Bt3,
                       int N) {
    int bid = blockIdx.x;
    int npadx = (N * KP1 + 255) / 256;
    if (bid < npadx) {
        int idx = bid * 256 + (int)threadIdx.x;
        if (idx < N * KP1) {
            int node = idx >> 6, k = idx & 63;
            Xs[idx] = (k < IN_F) ? f2bf(dinv[node] * x[node * IN_F + k]) : (unsigned short)0;
        }
        return;
    }
    bid -= npadx;
    if (bid < (HID * KP1) / 256) {          // Bt1 [256][64]
        int idx = bid * 256 + (int)threadIdx.x;
        int nn = idx >> 6, k = idx & 63;
        Bt1[idx] = (k < IN_F) ? f2bf(W1[k * HID + nn]) : (unsigned short)0;
        return;
    }
    bid -= (HID * KP1) / 256;
    if (bid < (HID * HID) / 256) {          // Bt2 [256][256]
        int idx = bid * 256 + (int)threadIdx.x;
        int nn = idx >> 8, k = idx & 255;
        Bt2[idx] = f2bf(W2[k * HID + nn]);
        return;
    }
    bid -= (HID * HID) / 256;
    {                                        // Bt3 [128][256]
        int idx = bid * 256 + (int)threadIdx.x;
        int nn = idx >> 8, k = idx & 255;
        Bt3[idx] = (nn < OUT_F) ? f2bf(W3[k * OUT_F + nn]) : (unsigned short)0;
    }
}

// ---- LDS-tiled GEMM (m97 structure) — layer 1 only --------------------------
__global__ __launch_bounds__(256) void k_gemm_lds(const unsigned short* __restrict__ A,
                                                  const unsigned short* __restrict__ Bt,
                                                  const float* __restrict__ dinv,
                                                  const float* __restrict__ bias,
                                                  unsigned short* __restrict__ C,
                                                  int K, int Nout,
                                                  int BIAS, int RELU, int SCALE) {
    __shared__ char lds[16384];   // A tile [128][32] bf16 @0, B tile @8192
    const int tid = threadIdx.x;
    const int wid = tid >> 6, lane = tid & 63;
    const int wm = wid & 1, wn = wid >> 1;
    const int quad = lane >> 4, ml = lane & 15;
    const int m0 = blockIdx.x * 128;
    const int n0g = blockIdx.y * 128;

    f32x4 acc[4][4];
    #pragma unroll
    for (int a = 0; a < 4; a++)
        #pragma unroll
        for (int b = 0; b < 4; b++) acc[a][b] = (f32x4){0.f, 0.f, 0.f, 0.f};

    for (int kk = 0; kk < K; kk += 32) {
        #pragma unroll
        for (int r = 0; r < 2; r++) {
            int c = r * 256 + tid;
            int row = c >> 2, q = c & 3;
            gl2lds16(A  + (size_t)(m0  + row) * K + kk + q * 8, lds + c * 16);
            gl2lds16(Bt + (size_t)(n0g + row) * K + kk + q * 8, lds + 8192 + c * 16);
        }
        __syncthreads();
        bf16x8 af[4], bfv[4];
        #pragma unroll
        for (int mf = 0; mf < 4; mf++)
            af[mf] = *(const bf16x8*)(lds + ((wm * 64 + mf * 16 + ml) * 64 + quad * 16));
        #pragma unroll
        for (int nf = 0; nf < 4; nf++)
            bfv[nf] = *(const bf16x8*)(lds + 8192 + ((wn * 64 + nf * 16 + ml) * 64 + quad * 16));
        #pragma unroll
        for (int mf = 0; mf < 4; mf++)
            #pragma unroll
            for (int nf = 0; nf < 4; nf++)
                acc[mf][nf] = __builtin_amdgcn_mfma_f32_16x16x32_bf16(af[mf], bfv[nf], acc[mf][nf], 0, 0, 0);
        __syncthreads();
    }

    #pragma unroll
    for (int mf = 0; mf < 4; mf++) {
        int r0 = m0 + wm * 64 + mf * 16 + quad * 4;
        float dd[4] = {1.f, 1.f, 1.f, 1.f};
        if (SCALE) { dd[0]=dinv[r0]; dd[1]=dinv[r0+1]; dd[2]=dinv[r0+2]; dd[3]=dinv[r0+3]; }
        #pragma unroll
        for (int nf = 0; nf < 4; nf++) {
            int col = n0g + wn * 64 + nf * 16 + ml;
            float bb = BIAS ? bias[col] : 0.f;
            #pragma unroll
            for (int i = 0; i < 4; i++) {
                float v = acc[mf][nf][i] + bb;
                if (RELU) v = fmaxf(v, 0.f);
                v *= dd[i];
                C[(size_t)(r0 + i) * Nout + col] = f2bf(v);
            }
        }
    }
}

// ---- FUSED GEMM2+GEMM3: G3 = dinv * (relu(Y2 W2 + b2) W3) -------------------
__global__ __launch_bounds__(256) void k_mlp23(const unsigned short* __restrict__ A,
                                               const unsigned short* __restrict__ B2t,
                                               const unsigned short* __restrict__ B3t,
                                               const float* __restrict__ b2,
                                               const float* __restrict__ dinv,
                                               unsigned short* __restrict__ G) {
    __shared__ char lds[65536];  // phase1 staging: A[128][32]@0, B2[256][32]@8192 (24KB)
                                 // then H2 [128][256] bf16 @0 (64KB, swizzled)
    const int tid = threadIdx.x;
    const int wid = tid >> 6, lane = tid & 63;
    const int wm = wid & 1, wn = wid >> 1;
    const int quad = lane >> 4, ml = lane & 15;
    const int m0 = blockIdx.x * 128;

    f32x4 acc1[4][8];
    #pragma unroll
    for (int a = 0; a < 4; a++)
        #pragma unroll
        for (int b = 0; b < 8; b++) acc1[a][b] = (f32x4){0.f, 0.f, 0.f, 0.f};

    for (int kk = 0; kk < HID; kk += 32) {
        #pragma unroll
        for (int r = 0; r < 2; r++) {
            int c = r * 256 + tid;
            int row = c >> 2, q = c & 3;
            gl2lds16(A + (size_t)(m0 + row) * HID + kk + q * 8, lds + c * 16);
        }
        #pragma unroll
        for (int r = 0; r < 4; r++) {
            int c = r * 256 + tid;
            int nn = c >> 2, q = c & 3;
            gl2lds16(B2t + (size_t)nn * HID + kk + q * 8, lds + 8192 + c * 16);
        }
        __syncthreads();
        bf16x8 af[4], bv[8];
        #pragma unroll
        for (int mf = 0; mf < 4; mf++)
            af[mf] = *(const bf16x8*)(lds + ((wm * 64 + mf * 16 + ml) * 64 + quad * 16));
        #pragma unroll
        for (int nf = 0; nf < 8; nf++)
            bv[nf] = *(const bf16x8*)(lds + 8192 + ((wn * 128 + nf * 16 + ml) * 64 + quad * 16));
        #pragma unroll
        for (int mf = 0; mf < 4; mf++)
            #pragma unroll
            for (int nf = 0; nf < 8; nf++)
                acc1[mf][nf] = __builtin_amdgcn_mfma_f32_16x16x32_bf16(af[mf], bv[nf], acc1[mf][nf], 0, 0, 0);
        __syncthreads();
    }

    // H2 = relu(acc1 + b2) -> LDS bf16, swizzled byte ^= (row&7)<<4
    #pragma unroll
    for (int nf = 0; nf < 8; nf++) {
        int col = wn * 128 + nf * 16 + ml;
        float bb = b2[col];
        #pragma unroll
        for (int mf = 0; mf < 4; mf++) {
            int rl = wm * 64 + mf * 16 + quad * 4;
            #pragma unroll
            for (int i = 0; i < 4; i++) {
                int row = rl + i;
                int byte = (row * 512 + col * 2) ^ ((row & 7) << 4);
                *(unsigned short*)(lds + byte) = f2bf(fmaxf(acc1[mf][nf][i] + bb, 0.f));
            }
        }
    }
    __syncthreads();

    // phase 2: G3 tile (128x128), A from H2-LDS, B direct from global Bt3
    f32x4 acc2[4][4];
    #pragma unroll
    for (int a = 0; a < 4; a++)
        #pragma unroll
        for (int b = 0; b < 4; b++) acc2[a][b] = (f32x4){0.f, 0.f, 0.f, 0.f};

    for (int kk = 0; kk < HID; kk += 32) {
        bf16x8 af2[4], bv2[4];
        #pragma unroll
        for (int mf = 0; mf < 4; mf++) {
            int row = wm * 64 + mf * 16 + ml;
            int byte = (row * 512 + kk * 2 + quad * 16) ^ ((row & 7) << 4);
            af2[mf] = *(const bf16x8*)(lds + byte);
        }
        #pragma unroll
        for (int nf = 0; nf < 4; nf++)
            bv2[nf] = *(const bf16x8*)(B3t + (size_t)(wn * 64 + nf * 16 + ml) * HID + kk + quad * 8);
        #pragma unroll
        for (int mf = 0; mf < 4; mf++)
            #pragma unroll
            for (int nf = 0; nf < 4; nf++)
                acc2[mf][nf] = __builtin_amdgcn_mfma_f32_16x16x32_bf16(af2[mf], bv2[nf], acc2[mf][nf], 0, 0, 0);
    }

    #pragma unroll
    for (int mf = 0; mf < 4; mf++) {
        int r0 = m0 + wm * 64 + mf * 16 + quad * 4;
        float dd[4] = {dinv[r0], dinv[r0+1], dinv[r0+2], dinv[r0+3]};
        #pragma unroll
        for (int nf = 0; nf < 4; nf++) {
            int col = wn * 64 + nf * 16 + ml;
            #pragma unroll
            for (int i = 0; i < 4; i++)
                G[(size_t)(r0 + i) * NP3 + col] = f2bf(acc2[mf][nf][i] * dd[i]);
        }
    }
}

// ---- aggregation kernels ----------------------------------------------------
// 16B/lane gathers, masked unroll-4 edge loop (tail lanes re-read last edge row
// -> L1 hit; fma-masked with 0).

__device__ __forceinline__ int rclamp(int r, int N) { return min(max(r, 0), N - 1); }

// aggx: rows 64 bf16 = 128B (1 line, no split) -> 8 lanes/row, 8 nodes/wave.
__global__ void k_aggx(const unsigned short* __restrict__ Xs,
                       const int* __restrict__ offs, const int* __restrict__ rowidx,
                       const float* __restrict__ dinv, unsigned short* __restrict__ Y, int N) {
    int wid = threadIdx.x >> 6, lane = threadIdx.x & 63;
    int sub = lane >> 3, sl = lane & 7;
    int node = blockIdx.x * 32 + wid * 8 + sub;
    int nc = min(node, N - 1);
    int c = sl * 8;
    bf16x8 s = *(const bf16x8*)(Xs + (size_t)nc * KP1 + c);
    float a[8];
    #pragma unroll
    for (int k = 0; k < 8; k++) a[k] = bf2f((unsigned short)s[k]);
    int e = offs[nc], end = offs[nc + 1];
    if (node >= N) { e = 0; end = 0; }
    while (__any(e < end)) {
        int r[4]; float m[4];
        #pragma unroll
        for (int j = 0; j < 4; j++) {
            int idx = e + j;
            m[j] = (idx < end) ? 1.f : 0.f;
            idx = min(idx, end - 1); idx = max(idx, 0);
            r[j] = rclamp(rowidx[idx], N);
        }
        bf16x8 u[4];
        #pragma unroll
        for (int j = 0; j < 4; j++)
            u[j] = *(const bf16x8*)(Xs + (size_t)r[j] * KP1 + c);
        #pragma unroll
        for (int j = 0; j < 4; j++)
            #pragma unroll
            for (int k = 0; k < 8; k++)
                a[k] = fmaf(bf2f((unsigned short)u[j][k]), m[j], a[k]);
        e += 4;
    }
    if (node < N) {
        float dv = dinv[node];
        bf16x8 o;
        #pragma unroll
        for (int k = 0; k < 8; k++) o[k] = (short)f2bf(a[k] * dv);
        *(bf16x8*)(Y + (size_t)node * KP1 + c) = o;
    }
}

// agg256s: FEATURE-SPLIT gather, 256-wide rows. 4 chunks of 64 bf16 (128B line);
// cell = bid&7: chunk = cell>>1, dest-half = cell&1. 8 lanes/chunk-row,
// 8 nodes/wave, 32/block. Per-XCD slab 12.8MB (r3-proven: FETCH ~329MB, 107us).
__global__ void k_agg256s(const unsigned short* __restrict__ Hn,
                          const int* __restrict__ offs, const int* __restrict__ rowidx,
                          const float* __restrict__ dinv, unsigned short* __restrict__ Y,
                          int N, int half_n) {
    int cell = blockIdx.x & 7;
    int chunk = cell >> 1, half = cell & 1;
    int idx = blockIdx.x >> 3;
    int wid = threadIdx.x >> 6, lane = threadIdx.x & 63;
    int sub = lane >> 3, sl = lane & 7;
    int node = half * half_n + idx * 32 + wid * 8 + sub;
    int hi_end = min((half + 1) * half_n, N);
    int ok = node < hi_end;
    int nc = ok ? node : hi_end - 1;
    int c = chunk * 64 + sl * 8;
    bf16x8 s = *(const bf16x8*)(Hn + (size_t)nc * HID + c);
    float a[8];
    #pragma unroll
    for (int k = 0; k < 8; k++) a[k] = bf2f((unsigned short)s[k]);
    int e = offs[nc], end = offs[nc + 1];
    if (!ok) { e = 0; end = 0; }
    while (__any(e < end)) {
        int r[4]; float m[4];
        #pragma unroll
        for (int j = 0; j < 4; j++) {
            int idx2 = e + j;
            m[j] = (idx2 < end) ? 1.f : 0.f;
            idx2 = min(idx2, end - 1); idx2 = max(idx2, 0);
            r[j] = rclamp(rowidx[idx2], N);
        }
        bf16x8 u[4];
        #pragma unroll
        for (int j = 0; j < 4; j++)
            u[j] = *(const bf16x8*)(Hn + (size_t)r[j] * HID + c);
        #pragma unroll
        for (int j = 0; j < 4; j++)
            #pragma unroll
            for (int k = 0; k < 8; k++)
                a[k] = fmaf(bf2f((unsigned short)u[j][k]), m[j], a[k]);
        e += 4;
    }
    if (ok) {
        float dv = dinv[node];
        bf16x8 o;
        #pragma unroll
        for (int k = 0; k < 8; k++) o[k] = (short)f2bf(a[k] * dv);
        *(bf16x8*)(Y + (size_t)node * HID + c) = o;
    }
}

// aggouts: FEATURE-SPLIT gather, 128-wide rows. 2 chunks of 64 bf16 (128B line)
// x 4 dest-quarters; cell = bid&7: chunk = cell>>2, quarter = cell&3.
// Per-XCD slab 3.2MB -- fits L2 (r3-proven).
__global__ void k_aggouts(const unsigned short* __restrict__ G,
                          const int* __restrict__ offs, const int* __restrict__ rowidx,
                          const float* __restrict__ dinv, const float* __restrict__ bias,
                          float* __restrict__ out, int N, int quar_n) {
    int cell = blockIdx.x & 7;
    int chunk = cell >> 2, quar = cell & 3;
    int idx = blockIdx.x >> 3;
    int wid = threadIdx.x >> 6, lane = threadIdx.x & 63;
    int sub = lane >> 3, sl = lane & 7;
    int node = quar * quar_n + idx * 32 + wid * 8 + sub;
    int hi_end = min((quar + 1) * quar_n, N);
    int ok = node < hi_end;
    int nc = ok ? node : hi_end - 1;
    int c = chunk * 64 + sl * 8;
    bf16x8 s = *(const bf16x8*)(G + (size_t)nc * NP3 + c);
    float a[8];
    #pragma unroll
    for (int k = 0; k < 8; k++) a[k] = bf2f((unsigned short)s[k]);
    int e = offs[nc], end = offs[nc + 1];
    if (!ok) { e = 0; end = 0; }
    while (__any(e < end)) {
        int r[4]; float m[4];
        #pragma unroll
        for (int j = 0; j < 4; j++) {
            int idx2 = e + j;
            m[j] = (idx2 < end) ? 1.f : 0.f;
            idx2 = min(idx2, end - 1); idx2 = max(idx2, 0);
            r[j] = rclamp(rowidx[idx2], N);
        }
        bf16x8 u[4];
        #pragma unroll
        for (int j = 0; j < 4; j++)
            u[j] = *(const bf16x8*)(G + (size_t)r[j] * NP3 + c);
        #pragma unroll
        for (int j = 0; j < 4; j++)
            #pragma unroll
            for (int k = 0; k < 8; k++)
                a[k] = fmaf(bf2f((unsigned short)u[j][k]), m[j], a[k]);
        e += 4;
    }
    if (ok) {
        float dv = dinv[node];
        #pragma unroll
        for (int k = 0; k < 8; k++) {
            int col = c + k;
            if (col < OUT_F)
                out[(size_t)node * OUT_F + col] = fmaf(a[k], dv, bias[col]);
        }
    }
}

// ---- launch -----------------------------------------------------------------

extern "C" void kernel_launch(void* const* d_in, const int* in_sizes, int n_in,
                              void* d_out, int out_size, void* d_ws, size_t ws_size,
                              hipStream_t stream) {
    const float* x  = (const float*)d_in[0];
    const int*   ei = (const int*)d_in[1];
    const float* W1 = (const float*)d_in[2];
    const float* b1 = (const float*)d_in[3];
    const float* W2 = (const float*)d_in[4];
    const float* b2 = (const float*)d_in[5];
    const float* W3 = (const float*)d_in[6];
    const float* b3 = (const float*)d_in[7];
    float* out = (float*)d_out;

    const int N = in_sizes[0] / IN_F;     // 100000
    const int E = in_sizes[1] / 2;        // 1600000

    char* w = (char*)d_ws;
    size_t off = 0;
    auto alloc = [&](size_t bytes) -> char* {
        char* p = w + off;
        off += (bytes + 255) & ~(size_t)255;
        return p;
    };
    int*   cnt    = (int*)  alloc((size_t)N * 4);
    int*   fillc  = (int*)  alloc((size_t)N * 4);   // adjacent to cnt: one memset
    int*   offs   = (int*)  alloc((size_t)(N + 1) * 4);
    float* dinv   = (float*)alloc((size_t)MPAD * 4); // padded: epilogues read r<MPAD
    int*   flag   = (int*)  alloc(256);
    int*   rowidx = (int*)  alloc((size_t)E * 4);    // no memset: every slot written
    unsigned short* Bt1 = (unsigned short*)alloc((size_t)HID * KP1 * 2);
    unsigned short* Bt2 = (unsigned short*)alloc((size_t)HID * HID * 2);
    unsigned short* Bt3 = (unsigned short*)alloc((size_t)NP3 * HID * 2);
    unsigned short* bufA = (unsigned short*)alloc((size_t)MPAD * HID * 2);
    unsigned short* bufB = (unsigned short*)alloc((size_t)MPAD * HID * 2);
    unsigned short* Xs  = bufA;    // prep out
    unsigned short* Y1  = bufB;    // aggx out
    unsigned short* H1s = bufA;    // gemm1 out (Xs dead)
    unsigned short* Y2  = bufB;    // agg256s out (Y1 dead)
    unsigned short* G3  = bufA;    // mlp23 out (H1s dead)

    // one memset covers cnt + pad + fillc (contiguous in ws)
    size_t msz = (size_t)((char*)fillc - (char*)cnt) + (size_t)N * 4;
    hipMemsetAsync(cnt, 0, msz, stream);

    k_detect<<<1, 64, 0, stream>>>(ei, flag, N);
    k_count<<<(E + 255) / 256, 256, 0, stream>>>(ei, flag, cnt, E, N);
    k_scan<<<1, 1024, 0, stream>>>(cnt, offs, dinv, N);
    int rng = (N + 7) / 8;
    k_fill8<<<8 * ((E + 255) / 256), 256, 0, stream>>>(ei, flag, offs, fillc, rowidx, E, N, rng);

    int prep_grid = (N * KP1 + 255) / 256 + (HID * KP1) / 256 + (HID * HID) / 256 + (NP3 * HID) / 256;
    k_prep<<<prep_grid, 256, 0, stream>>>(x, dinv, Xs, W1, Bt1, W2, Bt2, W3, Bt3, N);

    // layer 1: aggregate-first, then GEMM (+b1, relu, *dinv)
    k_aggx<<<(N + 31) / 32, 256, 0, stream>>>(Xs, offs, rowidx, dinv, Y1, N);
    dim3 g1(MPAD / 128, HID / 128);
    k_gemm_lds<<<g1, 256, 0, stream>>>(Y1, Bt1, dinv, b1, H1s, KP1, HID, 1, 1, 1);
    // layer 2 aggregate (128B chunks, 4x2), then fused GEMM2+GEMM3
    int half_n = (N + 1) / 2;
    int bpc2 = (half_n + 31) / 32;
    k_agg256s<<<8 * bpc2, 256, 0, stream>>>(H1s, offs, rowidx, dinv, Y2, N, half_n);
    k_mlp23<<<MPAD / 128, 256, 0, stream>>>(Y2, Bt2, Bt3, b2, dinv, G3);
    // layer 3 aggregate (+b3), f32 out (128B chunks, 2x4)
    int quar_n = (N + 3) / 4;
    int bpc3 = (quar_n + 31) / 32;
    k_aggouts<<<8 * bpc3, 256, 0, stream>>>(G3, offs, rowidx, dinv, b3, out, N, quar_n);

    (void)n_in; (void)out_size; (void)ws_size;
}

// Round 7
// 562.785 us; speedup vs baseline: 1.4833x; 1.1045x over previous
//
#include <hip/hip_runtime.h>

// GCN 3-layer forward on MI355X.
// Pipeline (A_hat (X W) = (A_hat X) W):
//   aggx:  Y1 = A_hat X          GEMM1: H1s = dinv*relu(Y1 W1 + b1)
//   agg256s: Y2 = A_hat H1       MLP23: G3 = dinv*((relu(Y2 W2 + b2)) W3)  [fused]
//   aggouts: out = dinv[c]*(sum G3[r]+G3[c]) + b3 (f32)
// Gather wall (r0-r6): L2-fill path ~3.6-3.8 TB/s; FETCH bytes are the lever.
// Fetch granule 128B (r4). XCD cell map bid&7 (r3/r6-validated, reads+writes).
// NEW r7: SOURCE-SEGMENT bucketED CSR (S=4). Each node's edge list is stored
// as 4 sublists keyed by src/25000. Gather kernels loop segments OUTERmost:
// co-resident blocks of a cell walk the same 3.2MB segment slab (fits 4MiB L2)
// in rough lockstep -> fetch ~= compulsory instead of 3.2x (agg256s r6:
// 329MB/107us). aggx gets the same loop. CSR: cnt4/offs4/fillc4[4N];
// 3-phase grid-parallel scan (single-WG scan would triple its traffic);
// ei converted once to int32 col32/row32 (kills int64 half-line waste in
// count/fill8: fill8 ~300->~100MB).
// k_fill8 keeps r6's XCD-range-split writes (rowidx region per dest-range
// written by ONE XCD -> full-line writeback; r6: fill 120->~50us).
// MLP23 fusion: H2 tile in LDS (XOR-swizzle (row&7)<<4); W3 L2-resident.

#define IN_F 50
#define HID  256
#define OUT_F 121
#define KP1  64      // layer-1 width padded 50->64
#define NP3  128     // layer-3 N padded 121->128
#define MPAD 100096  // 782 * 128

typedef __attribute__((ext_vector_type(8))) short bf16x8;
typedef __attribute__((ext_vector_type(4))) float f32x4;

__device__ __forceinline__ float bf2f(unsigned short u) {
    union { unsigned int i; float f; } x; x.i = ((unsigned int)u) << 16; return x.f;
}
__device__ __forceinline__ unsigned short f2bf(float f) {
    union { float f; unsigned int i; } x; x.f = f;
    unsigned int r = x.i + 0x7FFFu + ((x.i >> 16) & 1u);  // RNE
    return (unsigned short)(r >> 16);
}

__device__ __forceinline__ void gl2lds16(const void* g, void* l) {
    __builtin_amdgcn_global_load_lds(
        (const __attribute__((address_space(1))) void*)g,
        (__attribute__((address_space(3))) void*)l, 16, 0, 0);
}

// ---- edge dtype detection (int64 vs int32), 64-lane parallel ----------------
__global__ void k_detect(const int* __restrict__ ei, int* __restrict__ flag, int N) {
    int i = threadIdx.x;
    int lo = ei[2 * i], hi = ei[2 * i + 1];
    int bad = (hi != 0) || ((unsigned)lo >= (unsigned)N);
    unsigned long long m = __ballot(bad);
    if (threadIdx.x == 0) *flag = (m == 0ULL) ? 1 : 0;
}

// ---- edge conversion: int64/int32 -> clamped int32 col/row streams ----------
__global__ void k_cvt(const int* __restrict__ ei, const int* __restrict__ flag,
                      int* __restrict__ col32, int* __restrict__ row32, int E, int N) {
    int t = blockIdx.x * blockDim.x + threadIdx.x;
    if (t >= E) return;
    int f = *flag;
    int c = f ? ei[2 * (E + t)] : ei[E + t];
    int r = f ? ei[2 * t] : ei[t];
    col32[t] = min(max(c, 0), N - 1);
    row32[t] = min(max(r, 0), N - 1);
}

// ---- CSR build (segment-bucketed: key = dest*4 + src/seglen) ----------------

__global__ void k_count4(const int* __restrict__ col32, const int* __restrict__ row32,
                         int* __restrict__ cnt4, int E, int seglen) {
    int t = blockIdx.x * blockDim.x + threadIdx.x;
    if (t >= E) return;
    int c = col32[t], r = row32[t];
    atomicAdd(&cnt4[c * 4 + r / seglen], 1);
}

// 3-phase parallel scan over 4N counters (per-node int4).
__global__ __launch_bounds__(1024) void k_scanA(const int* __restrict__ cnt4,
                                                int* __restrict__ bsum, int n) {
    __shared__ int ws[16];
    int tid = threadIdx.x, lane = tid & 63, wid = tid >> 6;
    int j0 = blockIdx.x * 4096 + tid * 4;
    int t = 0;
    #pragma unroll
    for (int j = 0; j < 4; j++) {
        int node = j0 + j;
        if (node < n) { int4 v = *(const int4*)(cnt4 + 4 * node); t += v.x + v.y + v.z + v.w; }
    }
    #pragma unroll
    for (int d = 1; d < 64; d <<= 1) t += __shfl_xor(t, d, 64);
    if (lane == 0) ws[wid] = t;
    __syncthreads();
    if (tid == 0) {
        int s = 0;
        #pragma unroll
        for (int j = 0; j < 16; j++) s += ws[j];
        bsum[blockIdx.x] = s;
    }
}

__global__ void k_scanB(const int* __restrict__ bsum, int* __restrict__ bbase,
                        int* __restrict__ offs4, int nb, int n4) {
    int lane = threadIdx.x;
    int v = (lane < nb) ? bsum[lane] : 0;
    int x = v;
    #pragma unroll
    for (int d = 1; d < 64; d <<= 1) { int y = __shfl_up(x, d, 64); if (lane >= d) x += y; }
    if (lane < nb) bbase[lane] = x - v;
    if (lane == nb - 1) offs4[n4] = x;
}

__global__ __launch_bounds__(1024) void k_scanC(const int* __restrict__ cnt4,
                                                const int* __restrict__ bbase,
                                                int* __restrict__ offs4,
                                                float* __restrict__ dinv, int n) {
    __shared__ int wsum[16];
    int tid = threadIdx.x, lane = tid & 63, wid = tid >> 6;
    int i0 = blockIdx.x * 4096 + tid * 4;
    int4 z = {0, 0, 0, 0};
    int4 c0 = (i0 + 0 < n) ? *(const int4*)(cnt4 + 4 * (i0 + 0)) : z;
    int4 c1 = (i0 + 1 < n) ? *(const int4*)(cnt4 + 4 * (i0 + 1)) : z;
    int4 c2 = (i0 + 2 < n) ? *(const int4*)(cnt4 + 4 * (i0 + 2)) : z;
    int4 c3 = (i0 + 3 < n) ? *(const int4*)(cnt4 + 4 * (i0 + 3)) : z;
    int v0 = c0.x + c0.y + c0.z + c0.w;
    int v1 = c1.x + c1.y + c1.z + c1.w;
    int v2 = c2.x + c2.y + c2.z + c2.w;
    int v3 = c3.x + c3.y + c3.z + c3.w;
    int s1 = v0 + v1, s2 = s1 + v2, tsum = s2 + v3;
    int x = tsum;
    #pragma unroll
    for (int d = 1; d < 64; d <<= 1) { int y = __shfl_up(x, d, 64); if (lane >= d) x += y; }
    if (lane == 63) wsum[wid] = x;
    __syncthreads();
    int wpre = 0;
    #pragma unroll
    for (int j = 0; j < 16; j++) wpre += (j < wid) ? wsum[j] : 0;
    int e0 = bbase[blockIdx.x] + wpre + x - tsum;
    if (i0 + 0 < n) { int4 o; o.x = e0;      o.y = o.x + c0.x; o.z = o.y + c0.y; o.w = o.z + c0.z;
                      *(int4*)(offs4 + 4 * (i0 + 0)) = o; dinv[i0 + 0] = rsqrtf((float)(v0 + 1)); }
    if (i0 + 1 < n) { int4 o; o.x = e0 + v0; o.y = o.x + c1.x; o.z = o.y + c1.y; o.w = o.z + c1.z;
                      *(int4*)(offs4 + 4 * (i0 + 1)) = o; dinv[i0 + 1] = rsqrtf((float)(v1 + 1)); }
    if (i0 + 2 < n) { int4 o; o.x = e0 + s1; o.y = o.x + c2.x; o.z = o.y + c2.y; o.w = o.z + c2.z;
                      *(int4*)(offs4 + 4 * (i0 + 2)) = o; dinv[i0 + 2] = rsqrtf((float)(v2 + 1)); }
    if (i0 + 3 < n) { int4 o; o.x = e0 + s2; o.y = o.x + c3.x; o.z = o.y + c3.y; o.w = o.z + c3.z;
                      *(int4*)(offs4 + 4 * (i0 + 3)) = o; dinv[i0 + 3] = rsqrtf((float)(v3 + 1)); }
}

// k_fill8: XCD-range-split CSR fill (r6-proven write locality) + seg buckets.
__global__ void k_fill8(const int* __restrict__ col32, const int* __restrict__ row32,
                        const int* __restrict__ offs4,
                        int* __restrict__ fillc4, int* __restrict__ rowidx,
                        int E, int N, int rng, int seglen) {
    int cell = blockIdx.x & 7;
    int t = (blockIdx.x >> 3) * blockDim.x + threadIdx.x;
    if (t >= E) return;
    int c = col32[t];
    int lo = cell * rng;
    int hi = min(lo + rng, N);
    if (c < lo || c >= hi) return;
    int r = row32[t];
    int key = c * 4 + r / seglen;
    int pos = offs4[key] + atomicAdd(&fillc4[key], 1);
    if ((unsigned)pos < (unsigned)E) rowidx[pos] = r;
}

// ---- input prep (padx + 3 weight transposes, one launch) --------------------
__global__ void k_prep(const float* __restrict__ x, const float* __restrict__ dinv,
                       unsigned short* __restrict__ Xs,
                       const float* __restrict__ W1, unsigned short* __restrict__ Bt1,
                       const float* __restrict__ W2, unsigned short* __restrict__ Bt2,
                       const float* __restrict__ W3, unsigned short* __restrict__ Bt3,
                       int N) {
    int bid = blockIdx.x;
    int npadx = (N * KP1 + 255) / 256;
    if (bid < npadx) {
        int idx = bid * 256 + (int)threadIdx.x;
        if (idx < N * KP1) {
            int node = idx >> 6, k = idx & 63;
            Xs[idx] = (k < IN_F) ? f2bf(dinv[node] * x[node * IN_F + k]) : (unsigned short)0;
        }
        return;
    }
    bid -= npadx;
    if (bid < (HID * KP1) / 256) {          // Bt1 [256][64]
        int idx = bid * 256 + (int)threadIdx.x;
        int nn = idx >> 6, k = idx & 63;
        Bt1[idx] = (k < IN_F) ? f2bf(W1[k * HID + nn]) : (unsigned short)0;
        return;
    }
    bid -= (HID * KP1) / 256;
    if (bid < (HID * HID) / 256) {          // Bt2 [256][256]
        int idx = bid * 256 + (int)threadIdx.x;
        int nn = idx >> 8, k = idx & 255;
        Bt2[idx] = f2bf(W2[k * HID + nn]);
        return;
    }
    bid -= (HID * HID) / 256;
    {                                        // Bt3 [128][256]
        int idx = bid * 256 + (int)threadIdx.x;
        int nn = idx >> 8, k = idx & 255;
        Bt3[idx] = (nn < OUT_F) ? f2bf(W3[k * OUT_F + nn]) : (unsigned short)0;
    }
}

// ---- LDS-tiled GEMM (m97 structure) — layer 1 only --------------------------
__global__ __launch_bounds__(256) void k_gemm_lds(const unsigned short* __restrict__ A,
                                                  const unsigned short* __restrict__ Bt,
                                                  const float* __restrict__ dinv,
                                                  const float* __restrict__ bias,
                                                  unsigned short* __restrict__ C,
                                                  int K, int Nout,
                                                  int BIAS, int RELU, int SCALE) {
    __shared__ char lds[16384];   // A tile [128][32] bf16 @0, B tile @8192
    const int tid = threadIdx.x;
    const int wid = tid >> 6, lane = tid & 63;
    const int wm = wid & 1, wn = wid >> 1;
    const int quad = lane >> 4, ml = lane & 15;
    const int m0 = blockIdx.x * 128;
    const int n0g = blockIdx.y * 128;

    f32x4 acc[4][4];
    #pragma unroll
    for (int a = 0; a < 4; a++)
        #pragma unroll
        for (int b = 0; b < 4; b++) acc[a][b] = (f32x4){0.f, 0.f, 0.f, 0.f};

    for (int kk = 0; kk < K; kk += 32) {
        #pragma unroll
        for (int r = 0; r < 2; r++) {
            int c = r * 256 + tid;
            int row = c >> 2, q = c & 3;
            gl2lds16(A  + (size_t)(m0  + row) * K + kk + q * 8, lds + c * 16);
            gl2lds16(Bt + (size_t)(n0g + row) * K + kk + q * 8, lds + 8192 + c * 16);
        }
        __syncthreads();
        bf16x8 af[4], bfv[4];
        #pragma unroll
        for (int mf = 0; mf < 4; mf++)
            af[mf] = *(const bf16x8*)(lds + ((wm * 64 + mf * 16 + ml) * 64 + quad * 16));
        #pragma unroll
        for (int nf = 0; nf < 4; nf++)
            bfv[nf] = *(const bf16x8*)(lds + 8192 + ((wn * 64 + nf * 16 + ml) * 64 + quad * 16));
        #pragma unroll
        for (int mf = 0; mf < 4; mf++)
            #pragma unroll
            for (int nf = 0; nf < 4; nf++)
                acc[mf][nf] = __builtin_amdgcn_mfma_f32_16x16x32_bf16(af[mf], bfv[nf], acc[mf][nf], 0, 0, 0);
        __syncthreads();
    }

    #pragma unroll
    for (int mf = 0; mf < 4; mf++) {
        int r0 = m0 + wm * 64 + mf * 16 + quad * 4;
        float dd[4] = {1.f, 1.f, 1.f, 1.f};
        if (SCALE) { dd[0]=dinv[r0]; dd[1]=dinv[r0+1]; dd[2]=dinv[r0+2]; dd[3]=dinv[r0+3]; }
        #pragma unroll
        for (int nf = 0; nf < 4; nf++) {
            int col = n0g + wn * 64 + nf * 16 + ml;
            float bb = BIAS ? bias[col] : 0.f;
            #pragma unroll
            for (int i = 0; i < 4; i++) {
                float v = acc[mf][nf][i] + bb;
                if (RELU) v = fmaxf(v, 0.f);
                v *= dd[i];
                C[(size_t)(r0 + i) * Nout + col] = f2bf(v);
            }
        }
    }
}

// ---- FUSED GEMM2+GEMM3: G3 = dinv * (relu(Y2 W2 + b2) W3) -------------------
__global__ __launch_bounds__(256) void k_mlp23(const unsigned short* __restrict__ A,
                                               const unsigned short* __restrict__ B2t,
                                               const unsigned short* __restrict__ B3t,
                                               const float* __restrict__ b2,
                                               const float* __restrict__ dinv,
                                               unsigned short* __restrict__ G) {
    __shared__ char lds[65536];  // phase1 staging: A[128][32]@0, B2[256][32]@8192 (24KB)
                                 // then H2 [128][256] bf16 @0 (64KB, swizzled)
    const int tid = threadIdx.x;
    const int wid = tid >> 6, lane = tid & 63;
    const int wm = wid & 1, wn = wid >> 1;
    const int quad = lane >> 4, ml = lane & 15;
    const int m0 = blockIdx.x * 128;

    f32x4 acc1[4][8];
    #pragma unroll
    for (int a = 0; a < 4; a++)
        #pragma unroll
        for (int b = 0; b < 8; b++) acc1[a][b] = (f32x4){0.f, 0.f, 0.f, 0.f};

    for (int kk = 0; kk < HID; kk += 32) {
        #pragma unroll
        for (int r = 0; r < 2; r++) {
            int c = r * 256 + tid;
            int row = c >> 2, q = c & 3;
            gl2lds16(A + (size_t)(m0 + row) * HID + kk + q * 8, lds + c * 16);
        }
        #pragma unroll
        for (int r = 0; r < 4; r++) {
            int c = r * 256 + tid;
            int nn = c >> 2, q = c & 3;
            gl2lds16(B2t + (size_t)nn * HID + kk + q * 8, lds + 8192 + c * 16);
        }
        __syncthreads();
        bf16x8 af[4], bv[8];
        #pragma unroll
        for (int mf = 0; mf < 4; mf++)
            af[mf] = *(const bf16x8*)(lds + ((wm * 64 + mf * 16 + ml) * 64 + quad * 16));
        #pragma unroll
        for (int nf = 0; nf < 8; nf++)
            bv[nf] = *(const bf16x8*)(lds + 8192 + ((wn * 128 + nf * 16 + ml) * 64 + quad * 16));
        #pragma unroll
        for (int mf = 0; mf < 4; mf++)
            #pragma unroll
            for (int nf = 0; nf < 8; nf++)
                acc1[mf][nf] = __builtin_amdgcn_mfma_f32_16x16x32_bf16(af[mf], bv[nf], acc1[mf][nf], 0, 0, 0);
        __syncthreads();
    }

    // H2 = relu(acc1 + b2) -> LDS bf16, swizzled byte ^= (row&7)<<4
    #pragma unroll
    for (int nf = 0; nf < 8; nf++) {
        int col = wn * 128 + nf * 16 + ml;
        float bb = b2[col];
        #pragma unroll
        for (int mf = 0; mf < 4; mf++) {
            int rl = wm * 64 + mf * 16 + quad * 4;
            #pragma unroll
            for (int i = 0; i < 4; i++) {
                int row = rl + i;
                int byte = (row * 512 + col * 2) ^ ((row & 7) << 4);
                *(unsigned short*)(lds + byte) = f2bf(fmaxf(acc1[mf][nf][i] + bb, 0.f));
            }
        }
    }
    __syncthreads();

    // phase 2: G3 tile (128x128), A from H2-LDS, B direct from global Bt3
    f32x4 acc2[4][4];
    #pragma unroll
    for (int a = 0; a < 4; a++)
        #pragma unroll
        for (int b = 0; b < 4; b++) acc2[a][b] = (f32x4){0.f, 0.f, 0.f, 0.f};

    for (int kk = 0; kk < HID; kk += 32) {
        bf16x8 af2[4], bv2[4];
        #pragma unroll
        for (int mf = 0; mf < 4; mf++) {
            int row = wm * 64 + mf * 16 + ml;
            int byte = (row * 512 + kk * 2 + quad * 16) ^ ((row & 7) << 4);
            af2[mf] = *(const bf16x8*)(lds + byte);
        }
        #pragma unroll
        for (int nf = 0; nf < 4; nf++)
            bv2[nf] = *(const bf16x8*)(B3t + (size_t)(wn * 64 + nf * 16 + ml) * HID + kk + quad * 8);
        #pragma unroll
        for (int mf = 0; mf < 4; mf++)
            #pragma unroll
            for (int nf = 0; nf < 4; nf++)
                acc2[mf][nf] = __builtin_amdgcn_mfma_f32_16x16x32_bf16(af2[mf], bv2[nf], acc2[mf][nf], 0, 0, 0);
    }

    #pragma unroll
    for (int mf = 0; mf < 4; mf++) {
        int r0 = m0 + wm * 64 + mf * 16 + quad * 4;
        float dd[4] = {dinv[r0], dinv[r0+1], dinv[r0+2], dinv[r0+3]};
        #pragma unroll
        for (int nf = 0; nf < 4; nf++) {
            int col = wn * 64 + nf * 16 + ml;
            #pragma unroll
            for (int i = 0; i < 4; i++)
                G[(size_t)(r0 + i) * NP3 + col] = f2bf(acc2[mf][nf][i] * dd[i]);
        }
    }
}

// ---- aggregation kernels ----------------------------------------------------
// 16B/lane gathers, masked unroll-4 edge loop; segment-outer loop confines the
// L2 working set to one 3.2MB source segment per phase.

// aggx: rows 64 bf16 = 128B -> 8 lanes/row, 8 nodes/wave; seg loop (slab/seg
// 3.2MB fits L2; all XCDs share the same segment per phase).
__global__ void k_aggx(const unsigned short* __restrict__ Xs,
                       const int* __restrict__ offs4, const int* __restrict__ rowidx,
                       const float* __restrict__ dinv, unsigned short* __restrict__ Y, int N) {
    int wid = threadIdx.x >> 6, lane = threadIdx.x & 63;
    int sub = lane >> 3, sl = lane & 7;
    int node = blockIdx.x * 32 + wid * 8 + sub;
    int nc = min(node, N - 1);
    int c = sl * 8;
    bf16x8 s = *(const bf16x8*)(Xs + (size_t)nc * KP1 + c);
    float a[8];
    #pragma unroll
    for (int k = 0; k < 8; k++) a[k] = bf2f((unsigned short)s[k]);
    int4 ob = *(const int4*)(offs4 + 4 * nc);
    int oe = offs4[4 * nc + 4];
    int st[5] = {ob.x, ob.y, ob.z, ob.w, oe};
    int live = node < N;
    #pragma unroll
    for (int sg = 0; sg < 4; sg++) {
        int e = st[sg], end = st[sg + 1];
        if (!live) { e = 0; end = 0; }
        while (__any(e < end)) {
            int r[4]; float m[4];
            #pragma unroll
            for (int j = 0; j < 4; j++) {
                int idx = e + j;
                m[j] = (idx < end) ? 1.f : 0.f;
                idx = min(idx, end - 1); idx = max(idx, 0);
                r[j] = rowidx[idx];
            }
            bf16x8 u[4];
            #pragma unroll
            for (int j = 0; j < 4; j++)
                u[j] = *(const bf16x8*)(Xs + (size_t)r[j] * KP1 + c);
            #pragma unroll
            for (int j = 0; j < 4; j++)
                #pragma unroll
                for (int k = 0; k < 8; k++)
                    a[k] = fmaf(bf2f((unsigned short)u[j][k]), m[j], a[k]);
            e += 4;
        }
    }
    if (node < N) {
        float dv = dinv[node];
        bf16x8 o;
        #pragma unroll
        for (int k = 0; k < 8; k++) o[k] = (short)f2bf(a[k] * dv);
        *(bf16x8*)(Y + (size_t)node * KP1 + c) = o;
    }
}

// agg256s: FEATURE-SPLIT (4 chunks x 2 dest-halves, cell=bid&7 -> XCD) +
// seg loop. Per phase per XCD: one 3.2MB segment of one 12.8MB chunk slab.
__global__ void k_agg256s(const unsigned short* __restrict__ Hn,
                          const int* __restrict__ offs4, const int* __restrict__ rowidx,
                          const float* __restrict__ dinv, unsigned short* __restrict__ Y,
                          int N, int half_n) {
    int cell = blockIdx.x & 7;
    int chunk = cell >> 1, half = cell & 1;
    int idx = blockIdx.x >> 3;
    int wid = threadIdx.x >> 6, lane = threadIdx.x & 63;
    int sub = lane >> 3, sl = lane & 7;
    int node = half * half_n + idx * 32 + wid * 8 + sub;
    int hi_end = min((half + 1) * half_n, N);
    int ok = node < hi_end;
    int nc = ok ? node : hi_end - 1;
    int c = chunk * 64 + sl * 8;
    bf16x8 s = *(const bf16x8*)(Hn + (size_t)nc * HID + c);
    float a[8];
    #pragma unroll
    for (int k = 0; k < 8; k++) a[k] = bf2f((unsigned short)s[k]);
    int4 ob = *(const int4*)(offs4 + 4 * nc);
    int oe = offs4[4 * nc + 4];
    int st[5] = {ob.x, ob.y, ob.z, ob.w, oe};
    #pragma unroll
    for (int sg = 0; sg < 4; sg++) {
        int e = st[sg], end = st[sg + 1];
        if (!ok) { e = 0; end = 0; }
        while (__any(e < end)) {
            int r[4]; float m[4];
            #pragma unroll
            for (int j = 0; j < 4; j++) {
                int idx2 = e + j;
                m[j] = (idx2 < end) ? 1.f : 0.f;
                idx2 = min(idx2, end - 1); idx2 = max(idx2, 0);
                r[j] = rowidx[idx2];
            }
            bf16x8 u[4];
            #pragma unroll
            for (int j = 0; j < 4; j++)
                u[j] = *(const bf16x8*)(Hn + (size_t)r[j] * HID + c);
            #pragma unroll
            for (int j = 0; j < 4; j++)
                #pragma unroll
                for (int k = 0; k < 8; k++)
                    a[k] = fmaf(bf2f((unsigned short)u[j][k]), m[j], a[k]);
            e += 4;
        }
    }
    if (ok) {
        float dv = dinv[node];
        bf16x8 o;
        #pragma unroll
        for (int k = 0; k < 8; k++) o[k] = (short)f2bf(a[k] * dv);
        *(bf16x8*)(Y + (size_t)node * HID + c) = o;
    }
}

// aggouts: FEATURE-SPLIT (2 chunks x 4 dest-quarters). Slab 3.2MB/XCD already
// fits L2 -> no seg loop; iterate full list [offs4[4nc], offs4[4nc+4]).
__global__ void k_aggouts(const unsigned short* __restrict__ G,
                          const int* __restrict__ offs4, const int* __restrict__ rowidx,
                          const float* __restrict__ dinv, const float* __restrict__ bias,
                          float* __restrict__ out, int N, int quar_n) {
    int cell = blockIdx.x & 7;
    int chunk = cell >> 2, quar = cell & 3;
    int idx = blockIdx.x >> 3;
    int wid = threadIdx.x >> 6, lane = threadIdx.x & 63;
    int sub = lane >> 3, sl = lane & 7;
    int node = quar * quar_n + idx * 32 + wid * 8 + sub;
    int hi_end = min((quar + 1) * quar_n, N);
    int ok = node < hi_end;
    int nc = ok ? node : hi_end - 1;
    int c = chunk * 64 + sl * 8;
    bf16x8 s = *(const bf16x8*)(G + (size_t)nc * NP3 + c);
    float a[8];
    #pragma unroll
    for (int k = 0; k < 8; k++) a[k] = bf2f((unsigned short)s[k]);
    int e = offs4[4 * nc], end = offs4[4 * nc + 4];
    if (!ok) { e = 0; end = 0; }
    while (__any(e < end)) {
        int r[4]; float m[4];
        #pragma unroll
        for (int j = 0; j < 4; j++) {
            int idx2 = e + j;
            m[j] = (idx2 < end) ? 1.f : 0.f;
            idx2 = min(idx2, end - 1); idx2 = max(idx2, 0);
            r[j] = rowidx[idx2];
        }
        bf16x8 u[4];
        #pragma unroll
        for (int j = 0; j < 4; j++)
            u[j] = *(const bf16x8*)(G + (size_t)r[j] * NP3 + c);
        #pragma unroll
        for (int j = 0; j < 4; j++)
            #pragma unroll
            for (int k = 0; k < 8; k++)
                a[k] = fmaf(bf2f((unsigned short)u[j][k]), m[j], a[k]);
        e += 4;
    }
    if (ok) {
        float dv = dinv[node];
        #pragma unroll
        for (int k = 0; k < 8; k++) {
            int col = c + k;
            if (col < OUT_F)
                out[(size_t)node * OUT_F + col] = fmaf(a[k], dv, bias[col]);
        }
    }
}

// ---- launch -----------------------------------------------------------------

extern "C" void kernel_launch(void* const* d_in, const int* in_sizes, int n_in,
                              void* d_out, int out_size, void* d_ws, size_t ws_size,
                              hipStream_t stream) {
    const float* x  = (const float*)d_in[0];
    const int*   ei = (const int*)d_in[1];
    const float* W1 = (const float*)d_in[2];
    const float* b1 = (const float*)d_in[3];
    const float* W2 = (const float*)d_in[4];
    const float* b2 = (const float*)d_in[5];
    const float* W3 = (const float*)d_in[6];
    const float* b3 = (const float*)d_in[7];
    float* out = (float*)d_out;

    const int N = in_sizes[0] / IN_F;     // 100000
    const int E = in_sizes[1] / 2;        // 1600000

    char* w = (char*)d_ws;
    size_t off = 0;
    auto alloc = [&](size_t bytes) -> char* {
        char* p = w + off;
        off += (bytes + 255) & ~(size_t)255;
        return p;
    };
    int*   cnt4   = (int*)  alloc((size_t)N * 16);   // 4N counters
    int*   fillc4 = (int*)  alloc((size_t)N * 16);   // adjacent to cnt4: one memset
    int*   offs4  = (int*)  alloc((size_t)(4 * N + 1) * 4);
    float* dinv   = (float*)alloc((size_t)MPAD * 4); // padded: epilogues read r<MPAD
    int*   flag   = (int*)  alloc(256);
    int*   bsum   = (int*)  alloc(256);
    int*   bbase  = (int*)  alloc(256);
    int*   col32  = (int*)  alloc((size_t)E * 4);
    int*   row32  = (int*)  alloc((size_t)E * 4);
    int*   rowidx = (int*)  alloc((size_t)E * 4);    // no memset: every slot written
    unsigned short* Bt1 = (unsigned short*)alloc((size_t)HID * KP1 * 2);
    unsigned short* Bt2 = (unsigned short*)alloc((size_t)HID * HID * 2);
    unsigned short* Bt3 = (unsigned short*)alloc((size_t)NP3 * HID * 2);
    unsigned short* bufA = (unsigned short*)alloc((size_t)MPAD * HID * 2);
    unsigned short* bufB = (unsigned short*)alloc((size_t)MPAD * HID * 2);
    unsigned short* Xs  = bufA;    // prep out
    unsigned short* Y1  = bufB;    // aggx out
    unsigned short* H1s = bufA;    // gemm1 out (Xs dead)
    unsigned short* Y2  = bufB;    // agg256s out (Y1 dead)
    unsigned short* G3  = bufA;    // mlp23 out (H1s dead)

    // one memset covers cnt4 + fillc4 (contiguous in ws)
    size_t msz = (size_t)((char*)fillc4 - (char*)cnt4) + (size_t)N * 16;
    hipMemsetAsync(cnt4, 0, msz, stream);

    const int seglen = (N + 3) / 4;          // 25000
    const int nsc = (N + 4095) / 4096;       // 25 scan blocks

    k_detect<<<1, 64, 0, stream>>>(ei, flag, N);
    k_cvt<<<(E + 255) / 256, 256, 0, stream>>>(ei, flag, col32, row32, E, N);
    k_count4<<<(E + 255) / 256, 256, 0, stream>>>(col32, row32, cnt4, E, seglen);
    k_scanA<<<nsc, 1024, 0, stream>>>(cnt4, bsum, N);
    k_scanB<<<1, 64, 0, stream>>>(bsum, bbase, offs4, nsc, 4 * N);
    k_scanC<<<nsc, 1024, 0, stream>>>(cnt4, bbase, offs4, dinv, N);
    int rng = (N + 7) / 8;
    k_fill8<<<8 * ((E + 255) / 256), 256, 0, stream>>>(col32, row32, offs4, fillc4, rowidx, E, N, rng, seglen);

    int prep_grid = (N * KP1 + 255) / 256 + (HID * KP1) / 256 + (HID * HID) / 256 + (NP3 * HID) / 256;
    k_prep<<<prep_grid, 256, 0, stream>>>(x, dinv, Xs, W1, Bt1, W2, Bt2, W3, Bt3, N);

    // layer 1: aggregate-first (seg loop), then GEMM (+b1, relu, *dinv)
    k_aggx<<<(N + 31) / 32, 256, 0, stream>>>(Xs, offs4, rowidx, dinv, Y1, N);
    dim3 g1(MPAD / 128, HID / 128);
    k_gemm_lds<<<g1, 256, 0, stream>>>(Y1, Bt1, dinv, b1, H1s, KP1, HID, 1, 1, 1);
    // layer 2 aggregate (chunk x half cells, seg loop), then fused GEMM2+GEMM3
    int half_n = (N + 1) / 2;
    int bpc2 = (half_n + 31) / 32;
    k_agg256s<<<8 * bpc2, 256, 0, stream>>>(H1s, offs4, rowidx, dinv, Y2, N, half_n);
    k_mlp23<<<MPAD / 128, 256, 0, stream>>>(Y2, Bt2, Bt3, b2, dinv, G3);
    // layer 3 aggregate (+b3), f32 out (chunk x quarter cells)
    int quar_n = (N + 3) / 4;
    int bpc3 = (quar_n + 31) / 32;
    k_aggouts<<<8 * bpc3, 256, 0, stream>>>(G3, offs4, rowidx, dinv, b3, out, N, quar_n);

    (void)n_in; (void)out_size; (void)ws_size;
}